// Round 1
// baseline (2590.254 us; speedup 1.0000x reference)
//
#include <hip/hip_runtime.h>
#include <math.h>

#define N_NODES 50000
#define E_EDGES 400000
#define IN_DIM  256
#define HID     128
#define TT      3
#define RR      4
#define HH      8
#define DKK     16

__device__ __forceinline__ float geluf(float v){
    return 0.5f * v * (1.f + erff(v * 0.70710678118654752440f));
}

// ---------------- setup kernels ----------------

__global__ void k_hist_nodes(const int* __restrict__ nt, int* __restrict__ cntT, int n){
    int i = blockIdx.x*blockDim.x + threadIdx.x;
    if (i < n) atomicAdd(&cntT[nt[i]], 1);
}

__global__ void k_hist_edges(const int* __restrict__ edst, int* __restrict__ deg, int e){
    int i = blockIdx.x*blockDim.x + threadIdx.x;
    if (i < e) atomicAdd(&deg[edst[i]], 1);
}

__global__ void k_offT(const int* __restrict__ cntT, int* __restrict__ offT){
    if (threadIdx.x == 0 && blockIdx.x == 0){
        int a = 0;
        for (int t = 0; t < TT; ++t){ offT[t] = a; a += cntT[t]; }
        offT[TT] = a;
    }
}

__global__ void k_scatter_nodes(const int* __restrict__ nt, const int* __restrict__ offT,
                                int* __restrict__ tmpT, int* __restrict__ nperm, int n){
    int i = blockIdx.x*blockDim.x + threadIdx.x;
    if (i < n){
        int t = nt[i];
        int p = offT[t] + atomicAdd(&tmpT[t], 1);
        nperm[p] = i;
    }
}

// single-block exclusive scan of deg[0..n) -> off[0..n]
__global__ void k_scan(const int* __restrict__ deg, int* __restrict__ off, int n){
    __shared__ int sums[1024];
    int tid = threadIdx.x;
    int chunk = (n + 1023) >> 10;
    int st = tid*chunk, en = st + chunk; if (en > n) en = n;
    int s = 0;
    for (int i = st; i < en; ++i) s += deg[i];
    sums[tid] = s;
    __syncthreads();
    for (int o = 1; o < 1024; o <<= 1){
        int v = (tid >= o) ? sums[tid-o] : 0;
        __syncthreads();
        sums[tid] += v;
        __syncthreads();
    }
    int run = (tid == 0) ? 0 : sums[tid-1];
    for (int i = st; i < en; ++i){ off[i] = run; run += deg[i]; }
    if (tid == 1023) off[n] = run;
}

__global__ void k_scatter_edges(const int* __restrict__ edst, const int* __restrict__ off,
                                int* __restrict__ tmpN, int* __restrict__ eperm, int e){
    int i = blockIdx.x*blockDim.x + threadIdx.x;
    if (i < e){
        int d = edst[i];
        int p = off[d] + atomicAdd(&tmpN[d], 1);
        eperm[p] = i;
    }
}

// rel_msg [2][R][H][d][f] -> rmT [2][R][H][f][d]
__global__ void k_transpose_rmsg(const float* __restrict__ rm, float* __restrict__ rmT){
    int i = blockIdx.x*blockDim.x + threadIdx.x;
    const int tot = 2*RR*HH*DKK*DKK;
    if (i < tot){
        int f = i & 15;
        int d = (i >> 4) & 15;
        int rest = i >> 8; // (l,r,h)
        rmT[(rest*DKK + f)*DKK + d] = rm[i];
    }
}

// ---------------- typed GEMM: adapt (K=256, tanh) ----------------

__global__ __launch_bounds__(256) void k_adapt(
    const float* __restrict__ x, const float* __restrict__ W_, const float* __restrict__ b_,
    const int* __restrict__ nperm, const int* __restrict__ offT, const int* __restrict__ cntT,
    float* __restrict__ h0)
{
    const int t = blockIdx.y;
    const int cnt = cntT[t];
    const int base = blockIdx.x * 64;
    if (base >= cnt) return;
    __shared__ float xs[64][68];
    __shared__ int nid[64];
    const int tid = threadIdx.x;
    if (tid < 64){
        int ii = base + tid;
        nid[tid] = (ii < cnt) ? nperm[offT[t] + ii] : -1;
    }
    __syncthreads();
    const int j = tid & 127;
    const int half = tid >> 7;
    const float* __restrict__ W = W_ + (size_t)t*IN_DIM*HID;
    float acc[32];
#pragma unroll
    for (int r = 0; r < 32; ++r) acc[r] = 0.f;

    for (int kc = 0; kc < IN_DIM; kc += 64){
        for (int i = tid; i < 64*64; i += 256){
            int r = i >> 6, k = i & 63;
            int node = nid[r];
            xs[r][k] = (node >= 0) ? x[(size_t)node*IN_DIM + kc + k] : 0.f;
        }
        __syncthreads();
#pragma unroll 4
        for (int k = 0; k < 64; k += 4){
            float w0 = W[(size_t)(kc+k+0)*HID + j];
            float w1 = W[(size_t)(kc+k+1)*HID + j];
            float w2 = W[(size_t)(kc+k+2)*HID + j];
            float w3 = W[(size_t)(kc+k+3)*HID + j];
#pragma unroll
            for (int r = 0; r < 32; ++r){
                float4 xv = *(const float4*)&xs[half*32 + r][k];
                acc[r] = fmaf(xv.x, w0, acc[r]);
                acc[r] = fmaf(xv.y, w1, acc[r]);
                acc[r] = fmaf(xv.z, w2, acc[r]);
                acc[r] = fmaf(xv.w, w3, acc[r]);
            }
        }
        __syncthreads();
    }
    float bb = b_[t*HID + j];
#pragma unroll
    for (int r = 0; r < 32; ++r){
        int node = nid[half*32 + r];
        if (node >= 0) h0[(size_t)node*HID + j] = tanhf(acc[r] + bb);
    }
}

// ---------------- typed GEMM: K/Q/V (K=128) ----------------

__global__ __launch_bounds__(256) void k_kqv(
    const float* __restrict__ h,
    const float* __restrict__ Wk_, const float* __restrict__ bk_,
    const float* __restrict__ Wq_, const float* __restrict__ bq_,
    const float* __restrict__ Wv_, const float* __restrict__ bv_,
    const int* __restrict__ nperm, const int* __restrict__ offT, const int* __restrict__ cntT,
    float* __restrict__ Kb, float* __restrict__ Qb, float* __restrict__ Vb)
{
    const int z = blockIdx.z;
    const float* __restrict__ Wsel = (z == 0) ? Wk_ : (z == 1) ? Wq_ : Wv_;
    const float* __restrict__ bsel = (z == 0) ? bk_ : (z == 1) ? bq_ : bv_;
    float* __restrict__ osel = (z == 0) ? Kb : (z == 1) ? Qb : Vb;

    const int t = blockIdx.y;
    const int cnt = cntT[t];
    const int base = blockIdx.x * 64;
    if (base >= cnt) return;
    __shared__ float xs[64][68];
    __shared__ int nid[64];
    const int tid = threadIdx.x;
    if (tid < 64){
        int ii = base + tid;
        nid[tid] = (ii < cnt) ? nperm[offT[t] + ii] : -1;
    }
    __syncthreads();
    const int j = tid & 127;
    const int half = tid >> 7;
    const float* __restrict__ W = Wsel + (size_t)t*HID*HID;
    float acc[32];
#pragma unroll
    for (int r = 0; r < 32; ++r) acc[r] = 0.f;

    for (int kc = 0; kc < HID; kc += 64){
        for (int i = tid; i < 64*64; i += 256){
            int r = i >> 6, k = i & 63;
            int node = nid[r];
            xs[r][k] = (node >= 0) ? h[(size_t)node*HID + kc + k] : 0.f;
        }
        __syncthreads();
#pragma unroll 4
        for (int k = 0; k < 64; k += 4){
            float w0 = W[(size_t)(kc+k+0)*HID + j];
            float w1 = W[(size_t)(kc+k+1)*HID + j];
            float w2 = W[(size_t)(kc+k+2)*HID + j];
            float w3 = W[(size_t)(kc+k+3)*HID + j];
#pragma unroll
            for (int r = 0; r < 32; ++r){
                float4 xv = *(const float4*)&xs[half*32 + r][k];
                acc[r] = fmaf(xv.x, w0, acc[r]);
                acc[r] = fmaf(xv.y, w1, acc[r]);
                acc[r] = fmaf(xv.z, w2, acc[r]);
                acc[r] = fmaf(xv.w, w3, acc[r]);
            }
        }
        __syncthreads();
    }
    float bb = bsel[t*HID + j];
#pragma unroll
    for (int r = 0; r < 32; ++r){
        int node = nid[half*32 + r];
        if (node >= 0) osel[(size_t)node*HID + j] = acc[r] + bb;
    }
}

// ---------------- per-node attention + aggregation (1 wave / node) ----------------

__global__ __launch_bounds__(256) void k_attn(
    const float* __restrict__ Kb, const float* __restrict__ Qb, const float* __restrict__ Vb,
    const float* __restrict__ Ratt,   // [R][H][16][16] (layer slice)
    const float* __restrict__ rmT,    // [R][H][f][d]   (layer slice, transposed)
    const float* __restrict__ pri,    // [R][H]
    const int* __restrict__ off, const int* __restrict__ eperm,
    const int* __restrict__ esrc, const int* __restrict__ etype,
    float* __restrict__ agg)
{
    const int wid = threadIdx.x >> 6;
    const int n = blockIdx.x*4 + wid;
    if (n >= N_NODES) return;
    const int lane = threadIdx.x & 63;
    const int h = lane >> 3;
    const int jj = lane & 7;
    const int d0 = 2*jj;

    // load this head's q
    const float* qp = Qb + (size_t)n*HID + h*DKK;
    float qv[16];
#pragma unroll
    for (int u = 0; u < 4; ++u){
        float4 tq = *(const float4*)(qp + 4*u);
        qv[4*u+0] = tq.x; qv[4*u+1] = tq.y; qv[4*u+2] = tq.z; qv[4*u+3] = tq.w;
    }

    // q~[r][d0], q~[r][d0+1] = (Ratt[r,h] q)_{d0,d0+1} * pri * 1/sqrt(DK), in registers
    float qtA0, qtA1, qtA2, qtA3, qtB0, qtB1, qtB2, qtB3;
#pragma unroll
    for (int r = 0; r < RR; ++r){
        const float* ar = Ratt + (((size_t)(r*HH + h))*DKK + d0)*DKK;
        float s0 = 0.f, s1 = 0.f;
#pragma unroll
        for (int u = 0; u < 4; ++u){
            float4 a0 = *(const float4*)(ar + 4*u);
            float4 a1 = *(const float4*)(ar + DKK + 4*u);
            s0 += a0.x*qv[4*u+0] + a0.y*qv[4*u+1] + a0.z*qv[4*u+2] + a0.w*qv[4*u+3];
            s1 += a1.x*qv[4*u+0] + a1.y*qv[4*u+1] + a1.z*qv[4*u+2] + a1.w*qv[4*u+3];
        }
        float pr = pri[r*HH + h] * 0.25f; // INV_SQRT_DK = 0.25
        s0 *= pr; s1 *= pr;
        if      (r == 0){ qtA0 = s0; qtB0 = s1; }
        else if (r == 1){ qtA1 = s0; qtB1 = s1; }
        else if (r == 2){ qtA2 = s0; qtB2 = s1; }
        else            { qtA3 = s0; qtB3 = s1; }
    }

    float m = -INFINITY, l = 0.f, a0 = 0.f, a1 = 0.f;
    const int p0v = off[n], p1v = off[n+1];
    for (int p = p0v; p < p1v; ++p){
        int e = eperm[p];
        int s = esrc[e];
        int r = etype[e];
        const float* kp = Kb + (size_t)s*HID + h*DKK;
        float2 k2 = *(const float2*)(kp + d0);
        float qa = (r == 0) ? qtA0 : (r == 1) ? qtA1 : (r == 2) ? qtA2 : qtA3;
        float qb = (r == 0) ? qtB0 : (r == 1) ? qtB1 : (r == 2) ? qtB2 : qtB3;
        float part = k2.x*qa + k2.y*qb;
        part += __shfl_xor(part, 1);
        part += __shfl_xor(part, 2);
        part += __shfl_xor(part, 4);  // logit for head h, all 8 lanes of group

        const float* vp = Vb + (size_t)s*HID + h*DKK;
        float4 v0 = *(const float4*)(vp + 0);
        float4 v1 = *(const float4*)(vp + 4);
        float4 v2 = *(const float4*)(vp + 8);
        float4 v3 = *(const float4*)(vp + 12);
        const float* rm = rmT + (((size_t)(r*HH + h))*DKK + d0)*DKK;
        float4 m0 = *(const float4*)(rm + 0);
        float4 m1 = *(const float4*)(rm + 4);
        float4 m2 = *(const float4*)(rm + 8);
        float4 m3 = *(const float4*)(rm + 12);
        float4 n0 = *(const float4*)(rm + 16);
        float4 n1 = *(const float4*)(rm + 20);
        float4 n2 = *(const float4*)(rm + 24);
        float4 n3 = *(const float4*)(rm + 28);
        float vr0 = v0.x*m0.x + v0.y*m0.y + v0.z*m0.z + v0.w*m0.w
                  + v1.x*m1.x + v1.y*m1.y + v1.z*m1.z + v1.w*m1.w
                  + v2.x*m2.x + v2.y*m2.y + v2.z*m2.z + v2.w*m2.w
                  + v3.x*m3.x + v3.y*m3.y + v3.z*m3.z + v3.w*m3.w;
        float vr1 = v0.x*n0.x + v0.y*n0.y + v0.z*n0.z + v0.w*n0.w
                  + v1.x*n1.x + v1.y*n1.y + v1.z*n1.z + v1.w*n1.w
                  + v2.x*n2.x + v2.y*n2.y + v2.z*n2.z + v2.w*n2.w
                  + v3.x*n3.x + v3.y*n3.y + v3.z*n3.z + v3.w*n3.w;

        float mn = fmaxf(m, part);
        float sc = expf(m - mn);     // m=-inf first iter -> 0
        float pe = expf(part - mn);
        l = l*sc + pe;
        a0 = fmaf(pe, vr0, a0*sc);
        a1 = fmaf(pe, vr1, a1*sc);
        m = mn;
    }
    float inv = 1.f / fmaxf(l, 1e-9f);
    *(float2*)(agg + (size_t)n*HID + h*DKK + d0) = make_float2(a0*inv, a1*inv);
}

// ---------------- output GEMM: gelu(agg) @ Wa + blend (+LN+ReLU) ----------------

template<bool USE_LN>
__global__ __launch_bounds__(256) void k_out(
    const float* __restrict__ aggb, const float* __restrict__ Wa_, const float* __restrict__ ba_,
    const float* __restrict__ hin, const float* __restrict__ skipl,
    const float* __restrict__ gam, const float* __restrict__ bet,
    const int* __restrict__ nperm, const int* __restrict__ offT, const int* __restrict__ cntT,
    float* __restrict__ hout)
{
    const int t = blockIdx.y;
    const int cnt = cntT[t];
    const int base = blockIdx.x * 64;
    if (base >= cnt) return;
    __shared__ float smem[64*129];   // xs view stride 68, obuf view stride 129
    __shared__ int nid[64];
    __shared__ float mus[64], rstds[64];
    __shared__ float red1[4][64], red2[4][64];
    const int tid = threadIdx.x;
    if (tid < 64){
        int ii = base + tid;
        nid[tid] = (ii < cnt) ? nperm[offT[t] + ii] : -1;
    }
    __syncthreads();
    const int j = tid & 127;
    const int half = tid >> 7;
    const float* __restrict__ W = Wa_ + (size_t)t*HID*HID;
    float acc[32];
#pragma unroll
    for (int r = 0; r < 32; ++r) acc[r] = 0.f;

    for (int kc = 0; kc < HID; kc += 64){
        for (int i = tid; i < 64*64; i += 256){
            int r = i >> 6, k = i & 63;
            int node = nid[r];
            smem[r*68 + k] = (node >= 0) ? geluf(aggb[(size_t)node*HID + kc + k]) : 0.f;
        }
        __syncthreads();
#pragma unroll 4
        for (int k = 0; k < 64; k += 4){
            float w0 = W[(size_t)(kc+k+0)*HID + j];
            float w1 = W[(size_t)(kc+k+1)*HID + j];
            float w2 = W[(size_t)(kc+k+2)*HID + j];
            float w3 = W[(size_t)(kc+k+3)*HID + j];
#pragma unroll
            for (int r = 0; r < 32; ++r){
                float4 xv = *(const float4*)&smem[(half*32 + r)*68 + k];
                acc[r] = fmaf(xv.x, w0, acc[r]);
                acc[r] = fmaf(xv.y, w1, acc[r]);
                acc[r] = fmaf(xv.z, w2, acc[r]);
                acc[r] = fmaf(xv.w, w3, acc[r]);
            }
        }
        __syncthreads();
    }
    const float alpha = 1.f / (1.f + expf(-skipl[t]));
    const float bb = ba_[t*HID + j];
    // blend in place into acc[] (acc = out value pre-norm)
#pragma unroll
    for (int r = 0; r < 32; ++r){
        int node = nid[half*32 + r];
        if (node >= 0){
            float xv = hin[(size_t)node*HID + j];
            acc[r] = (acc[r] + bb)*alpha + xv*(1.f - alpha);
        } else acc[r] = 0.f;
    }
    if (USE_LN){
#pragma unroll
        for (int r = 0; r < 32; ++r)
            smem[(half*32 + r)*129 + j] = acc[r];
        __syncthreads();
        {
            int row = tid & 63, qq = tid >> 6;
            float s = 0.f, s2 = 0.f;
#pragma unroll
            for (int i2 = 0; i2 < 32; ++i2){
                float v = smem[row*129 + qq*32 + i2];
                s += v; s2 += v*v;
            }
            red1[qq][row] = s; red2[qq][row] = s2;
        }
        __syncthreads();
        if (tid < 64){
            float su = red1[0][tid] + red1[1][tid] + red1[2][tid] + red1[3][tid];
            float sq = red2[0][tid] + red2[1][tid] + red2[2][tid] + red2[3][tid];
            float mu = su * (1.f/128.f);
            float var = sq * (1.f/128.f) - mu*mu;
            mus[tid] = mu;
            rstds[tid] = rsqrtf(var + 1e-5f);
        }
        __syncthreads();
        float g = gam[t*HID + j], be = bet[t*HID + j];
#pragma unroll
        for (int r = 0; r < 32; ++r){
            int node = nid[half*32 + r];
            if (node >= 0){
                float val = (acc[r] - mus[half*32 + r])*rstds[half*32 + r]*g + be;
                hout[(size_t)node*HID + j] = fmaxf(val, 0.f);  // ReLU after layer-0
            }
        }
    } else {
#pragma unroll
        for (int r = 0; r < 32; ++r){
            int node = nid[half*32 + r];
            if (node >= 0) hout[(size_t)node*HID + j] = acc[r];
        }
    }
}

// ---------------- launch ----------------

extern "C" void kernel_launch(void* const* d_in, const int* in_sizes, int n_in,
                              void* d_out, int out_size, void* d_ws, size_t ws_size,
                              hipStream_t stream)
{
    const float* x         = (const float*)d_in[0];
    const int*   node_types= (const int*)  d_in[1];
    const int*   edge_index= (const int*)  d_in[2];
    const int*   edge_types= (const int*)  d_in[3];
    const float* W_adapt   = (const float*)d_in[4];
    const float* b_adapt   = (const float*)d_in[5];
    const float* Wk        = (const float*)d_in[6];
    const float* bk        = (const float*)d_in[7];
    const float* Wq        = (const float*)d_in[8];
    const float* bq        = (const float*)d_in[9];
    const float* Wv        = (const float*)d_in[10];
    const float* bv        = (const float*)d_in[11];
    const float* Wa        = (const float*)d_in[12];
    const float* ba        = (const float*)d_in[13];
    const float* rel_pri   = (const float*)d_in[14];
    const float* rel_att   = (const float*)d_in[15];
    const float* rel_msg   = (const float*)d_in[16];
    const float* skip      = (const float*)d_in[17];
    const float* ln_g      = (const float*)d_in[18];
    const float* ln_b      = (const float*)d_in[19];
    float* out = (float*)d_out;

    char* p = (char*)d_ws;
    auto alloc = [&](size_t bytes) -> void* {
        void* q = (void*)p;
        p += (bytes + 255) & ~(size_t)255;
        return q;
    };
    float* h0   = (float*)alloc((size_t)N_NODES*HID*4);
    float* Kb   = (float*)alloc((size_t)N_NODES*HID*4);
    float* Qb   = (float*)alloc((size_t)N_NODES*HID*4);
    float* Vb   = (float*)alloc((size_t)N_NODES*HID*4);
    float* aggb = (float*)alloc((size_t)N_NODES*HID*4);
    float* rmT  = (float*)alloc((size_t)2*RR*HH*DKK*DKK*4);
    int* ib     = (int*)alloc((size_t)(2*N_NODES + 8)*4);
    int* deg  = ib;
    int* tmpN = ib + N_NODES;
    int* cntT = ib + 2*N_NODES;
    int* tmpT = ib + 2*N_NODES + 4;
    int* off   = (int*)alloc((size_t)(N_NODES+1)*4);
    int* offT  = (int*)alloc(16);
    int* eperm = (int*)alloc((size_t)E_EDGES*4);
    int* nperm = (int*)alloc((size_t)N_NODES*4);

    const int* esrc = edge_index;
    const int* edst = edge_index + E_EDGES;

    hipMemsetAsync(ib, 0, (size_t)(2*N_NODES + 8)*4, stream);
    k_hist_nodes<<<(N_NODES+255)/256, 256, 0, stream>>>(node_types, cntT, N_NODES);
    k_hist_edges<<<(E_EDGES+255)/256, 256, 0, stream>>>(edst, deg, E_EDGES);
    k_offT<<<1, 1, 0, stream>>>(cntT, offT);
    k_scan<<<1, 1024, 0, stream>>>(deg, off, N_NODES);
    k_scatter_nodes<<<(N_NODES+255)/256, 256, 0, stream>>>(node_types, offT, tmpT, nperm, N_NODES);
    k_scatter_edges<<<(E_EDGES+255)/256, 256, 0, stream>>>(edst, off, tmpN, eperm, E_EDGES);
    k_transpose_rmsg<<<(2*RR*HH*DKK*DKK+255)/256, 256, 0, stream>>>(rel_msg, rmT);

    dim3 gg((N_NODES+63)/64, TT);
    k_adapt<<<gg, 256, 0, stream>>>(x, W_adapt, b_adapt, nperm, offT, cntT, h0);

    for (int l = 0; l < 2; ++l){
        const float* hin = (l == 0) ? h0 : out;
        const size_t WOFF = (size_t)l*TT*HID*HID;
        const size_t BOFF = (size_t)l*TT*HID;
        dim3 g3((N_NODES+63)/64, TT, 3);
        k_kqv<<<g3, 256, 0, stream>>>(hin, Wk+WOFF, bk+BOFF, Wq+WOFF, bq+BOFF, Wv+WOFF, bv+BOFF,
                                      nperm, offT, cntT, Kb, Qb, Vb);
        k_attn<<<N_NODES/4, 256, 0, stream>>>(Kb, Qb, Vb,
            rel_att + (size_t)l*RR*HH*DKK*DKK,
            rmT + (size_t)l*RR*HH*DKK*DKK,
            rel_pri + (size_t)l*RR*HH,
            off, eperm, esrc, edge_types, aggb);
        if (l == 0)
            k_out<true><<<gg, 256, 0, stream>>>(aggb, Wa+WOFF, ba+BOFF, hin, skip + l*TT,
                                                ln_g, ln_b, nperm, offT, cntT, out);
        else
            k_out<false><<<gg, 256, 0, stream>>>(aggb, Wa+WOFF, ba+BOFF, hin, skip + l*TT,
                                                 ln_g, ln_b, nperm, offT, cntT, out);
    }
}

// Round 2
// 1997.356 us; speedup vs baseline: 1.2968x; 1.2968x over previous
//
#include <hip/hip_runtime.h>
#include <math.h>

#define N_NODES 50000
#define E_EDGES 400000
#define IN_DIM  256
#define HID     128
#define TT      3
#define RR      4
#define HH      8
#define DKK     16

__device__ __forceinline__ float geluf(float v){
    return 0.5f * v * (1.f + erff(v * 0.70710678118654752440f));
}

// ---------------- setup kernels ----------------

__global__ void k_hist_nodes(const int* __restrict__ nt, int* __restrict__ cntT, int n){
    int i = blockIdx.x*blockDim.x + threadIdx.x;
    if (i < n) atomicAdd(&cntT[nt[i]], 1);
}

__global__ void k_hist_edges(const int* __restrict__ edst, int* __restrict__ deg, int e){
    int i = blockIdx.x*blockDim.x + threadIdx.x;
    if (i < e) atomicAdd(&deg[edst[i]], 1);
}

__global__ void k_offT(const int* __restrict__ cntT, int* __restrict__ offT){
    if (threadIdx.x == 0 && blockIdx.x == 0){
        int a = 0;
        for (int t = 0; t < TT; ++t){ offT[t] = a; a += cntT[t]; }
        offT[TT] = a;
    }
}

__global__ void k_scatter_nodes(const int* __restrict__ nt, const int* __restrict__ offT,
                                int* __restrict__ tmpT, int* __restrict__ nperm, int n){
    int i = blockIdx.x*blockDim.x + threadIdx.x;
    if (i < n){
        int t = nt[i];
        int p = offT[t] + atomicAdd(&tmpT[t], 1);
        nperm[p] = i;
    }
}

// single-block exclusive scan of deg[0..n) -> off[0..n]
__global__ void k_scan(const int* __restrict__ deg, int* __restrict__ off, int n){
    __shared__ int sums[1024];
    int tid = threadIdx.x;
    int chunk = (n + 1023) >> 10;
    int st = tid*chunk, en = st + chunk; if (en > n) en = n;
    int s = 0;
    for (int i = st; i < en; ++i) s += deg[i];
    sums[tid] = s;
    __syncthreads();
    for (int o = 1; o < 1024; o <<= 1){
        int v = (tid >= o) ? sums[tid-o] : 0;
        __syncthreads();
        sums[tid] += v;
        __syncthreads();
    }
    int run = (tid == 0) ? 0 : sums[tid-1];
    for (int i = st; i < en; ++i){ off[i] = run; run += deg[i]; }
    if (tid == 1023) off[n] = run;
}

// sorted packed edges: epk[p] = src | (type<<16)  (src < 65536, type < 4)
__global__ void k_scatter_edges(const int* __restrict__ esrc, const int* __restrict__ edst,
                                const int* __restrict__ ety,
                                const int* __restrict__ off, int* __restrict__ tmpN,
                                int* __restrict__ epk, int e){
    int i = blockIdx.x*blockDim.x + threadIdx.x;
    if (i < e){
        int d = edst[i];
        int p = off[d] + atomicAdd(&tmpN[d], 1);
        epk[p] = esrc[i] | (ety[i] << 16);
    }
}

// rel_msg [2][R][H][d][f] -> rmT [2][R][H][f][d]
__global__ void k_transpose_rmsg(const float* __restrict__ rm, float* __restrict__ rmT){
    int i = blockIdx.x*blockDim.x + threadIdx.x;
    const int tot = 2*RR*HH*DKK*DKK;
    if (i < tot){
        int f = i & 15;
        int d = (i >> 4) & 15;
        int rest = i >> 8; // (l,r,h)
        rmT[(rest*DKK + f)*DKK + d] = rm[i];
    }
}

// ---------------- register-blocked typed GEMM bodies ----------------
// block: 64 rows x 128 cols, 256 threads; thread: 8 rows x 4 cols.
// rg = tid>>5 (row group, 8 rows), c4 = tid&31 (col group, 4 cols).

#define GEMM_CHUNK(BK) \
  _Pragma("unroll 2") \
  for (int k = 0; k < (BK); k += 4){ \
    float4 w0 = *(const float4*)&W[(size_t)(kc + k + 0)*HID + c0]; \
    float4 w1 = *(const float4*)&W[(size_t)(kc + k + 1)*HID + c0]; \
    float4 w2 = *(const float4*)&W[(size_t)(kc + k + 2)*HID + c0]; \
    float4 w3 = *(const float4*)&W[(size_t)(kc + k + 3)*HID + c0]; \
    _Pragma("unroll") \
    for (int rr = 0; rr < 8; ++rr){ \
      float4 xv = *(const float4*)&xs[rg8 + rr][k]; \
      float4 a = acc[rr]; \
      a.x = fmaf(xv.x, w0.x, a.x); a.y = fmaf(xv.x, w0.y, a.y); a.z = fmaf(xv.x, w0.z, a.z); a.w = fmaf(xv.x, w0.w, a.w); \
      a.x = fmaf(xv.y, w1.x, a.x); a.y = fmaf(xv.y, w1.y, a.y); a.z = fmaf(xv.y, w1.z, a.z); a.w = fmaf(xv.y, w1.w, a.w); \
      a.x = fmaf(xv.z, w2.x, a.x); a.y = fmaf(xv.z, w2.y, a.y); a.z = fmaf(xv.z, w2.z, a.z); a.w = fmaf(xv.z, w2.w, a.w); \
      a.x = fmaf(xv.w, w3.x, a.x); a.y = fmaf(xv.w, w3.y, a.y); a.z = fmaf(xv.w, w3.z, a.z); a.w = fmaf(xv.w, w3.w, a.w); \
      acc[rr] = a; \
    } \
  }

// ---------------- adapt: h0 = tanh(x @ W_adapt[t] + b), K=256 ----------------

__global__ __launch_bounds__(256) void k_adapt(
    const float* __restrict__ x, const float* __restrict__ W_, const float* __restrict__ b_,
    const int* __restrict__ nperm, const int* __restrict__ offT, const int* __restrict__ cntT,
    float* __restrict__ h0)
{
    const int t = blockIdx.y;
    const int cnt = cntT[t];
    const int base = blockIdx.x * 64;
    if (base >= cnt) return;
    __shared__ float xs[64][132];
    __shared__ int nid[64];
    const int tid = threadIdx.x;
    if (tid < 64){
        int ii = base + tid;
        nid[tid] = (ii < cnt) ? nperm[offT[t] + ii] : -1;
    }
    __syncthreads();
    const int c0  = (tid & 31) * 4;
    const int rg8 = (tid >> 5) * 8;
    const float* __restrict__ W = W_ + (size_t)t*IN_DIM*HID;
    float4 acc[8];
#pragma unroll
    for (int r = 0; r < 8; ++r) acc[r] = make_float4(0.f,0.f,0.f,0.f);

    for (int kc = 0; kc < IN_DIM; kc += 128){
        for (int i = tid; i < 64*32; i += 256){
            int row = i >> 5, k4 = i & 31;
            int node = nid[row];
            float4 val = make_float4(0.f,0.f,0.f,0.f);
            if (node >= 0) val = *(const float4*)&x[(size_t)node*IN_DIM + kc + k4*4];
            *(float4*)&xs[row][k4*4] = val;
        }
        __syncthreads();
        GEMM_CHUNK(128)
        __syncthreads();
    }
    float4 b4 = *(const float4*)&b_[t*HID + c0];
#pragma unroll
    for (int rr = 0; rr < 8; ++rr){
        int node = nid[rg8 + rr];
        if (node >= 0){
            float4 a = acc[rr];
            a.x = tanhf(a.x + b4.x); a.y = tanhf(a.y + b4.y);
            a.z = tanhf(a.z + b4.z); a.w = tanhf(a.w + b4.w);
            *(float4*)&h0[(size_t)node*HID + c0] = a;
        }
    }
}

// ---------------- K/Q/V GEMM (K=128) ----------------

__global__ __launch_bounds__(256) void k_kqv(
    const float* __restrict__ h,
    const float* __restrict__ Wk_, const float* __restrict__ bk_,
    const float* __restrict__ Wq_, const float* __restrict__ bq_,
    const float* __restrict__ Wv_, const float* __restrict__ bv_,
    const int* __restrict__ nperm, const int* __restrict__ offT, const int* __restrict__ cntT,
    float* __restrict__ Kb, float* __restrict__ Qb, float* __restrict__ Vb)
{
    const int z = blockIdx.z;
    const float* __restrict__ Wsel = (z == 0) ? Wk_ : (z == 1) ? Wq_ : Wv_;
    const float* __restrict__ bsel = (z == 0) ? bk_ : (z == 1) ? bq_ : bv_;
    float* __restrict__ osel = (z == 0) ? Kb : (z == 1) ? Qb : Vb;

    const int t = blockIdx.y;
    const int cnt = cntT[t];
    const int base = blockIdx.x * 64;
    if (base >= cnt) return;
    __shared__ float xs[64][132];
    __shared__ int nid[64];
    const int tid = threadIdx.x;
    if (tid < 64){
        int ii = base + tid;
        nid[tid] = (ii < cnt) ? nperm[offT[t] + ii] : -1;
    }
    __syncthreads();
    const int c0  = (tid & 31) * 4;
    const int rg8 = (tid >> 5) * 8;
    const float* __restrict__ W = Wsel + (size_t)t*HID*HID;
    float4 acc[8];
#pragma unroll
    for (int r = 0; r < 8; ++r) acc[r] = make_float4(0.f,0.f,0.f,0.f);

    {
        const int kc = 0;
        for (int i = tid; i < 64*32; i += 256){
            int row = i >> 5, k4 = i & 31;
            int node = nid[row];
            float4 val = make_float4(0.f,0.f,0.f,0.f);
            if (node >= 0) val = *(const float4*)&h[(size_t)node*HID + k4*4];
            *(float4*)&xs[row][k4*4] = val;
        }
        __syncthreads();
        GEMM_CHUNK(128)
    }
    float4 b4 = *(const float4*)&bsel[t*HID + c0];
#pragma unroll
    for (int rr = 0; rr < 8; ++rr){
        int node = nid[rg8 + rr];
        if (node >= 0){
            float4 a = acc[rr];
            a.x += b4.x; a.y += b4.y; a.z += b4.z; a.w += b4.w;
            *(float4*)&osel[(size_t)node*HID + c0] = a;
        }
    }
}

// ---------------- per-node attention, deferred Rmsg transform ----------------
// wave per node; lane = h*8 + jj, owns dims d0=2*jj, d0+1 of head h.
// online softmax per head; raw-v accumulated per relation type; Rmsg applied once at end.

#define EDGE_UPDATE(PK, K2, V2) { \
    int r_ = (PK) >> 16; \
    float qa = (r_==0) ? qtA0 : (r_==1) ? qtA1 : (r_==2) ? qtA2 : qtA3; \
    float qb = (r_==0) ? qtB0 : (r_==1) ? qtB1 : (r_==2) ? qtB2 : qtB3; \
    float part = fmaf((K2).x, qa, (K2).y*qb); \
    part += __shfl_xor(part, 1); \
    part += __shfl_xor(part, 2); \
    part += __shfl_xor(part, 4); \
    float mn = fmaxf(m, part); \
    float sc = __expf(m - mn); \
    float pe = __expf(part - mn); \
    l = fmaf(l, sc, pe); \
    float w0_ = (r_==0)?pe:0.f, w1_ = (r_==1)?pe:0.f, w2_ = (r_==2)?pe:0.f, w3_ = (r_==3)?pe:0.f; \
    aA0 = fmaf(w0_, (V2).x, aA0*sc); aB0 = fmaf(w0_, (V2).y, aB0*sc); \
    aA1 = fmaf(w1_, (V2).x, aA1*sc); aB1 = fmaf(w1_, (V2).y, aB1*sc); \
    aA2 = fmaf(w2_, (V2).x, aA2*sc); aB2 = fmaf(w2_, (V2).y, aB2*sc); \
    aA3 = fmaf(w3_, (V2).x, aA3*sc); aB3 = fmaf(w3_, (V2).y, aB3*sc); \
    m = mn; }

#define FINAL_R(AA, BB, RIDX) { \
    float y[16]; \
    _Pragma("unroll") \
    for (int u = 0; u < 8; ++u){ \
        y[2*u]   = __shfl((AA), (h<<3) + u); \
        y[2*u+1] = __shfl((BB), (h<<3) + u); \
    } \
    const float* rm = rmT + (((size_t)((RIDX)*HH + h))*DKK + d0)*DKK; \
    float4 A0 = *(const float4*)(rm + 0),  A1 = *(const float4*)(rm + 4); \
    float4 A2 = *(const float4*)(rm + 8),  A3 = *(const float4*)(rm + 12); \
    float4 B0 = *(const float4*)(rm + 16), B1 = *(const float4*)(rm + 20); \
    float4 B2 = *(const float4*)(rm + 24), B3 = *(const float4*)(rm + 28); \
    o0 += y[0]*A0.x + y[1]*A0.y + y[2]*A0.z + y[3]*A0.w \
        + y[4]*A1.x + y[5]*A1.y + y[6]*A1.z + y[7]*A1.w \
        + y[8]*A2.x + y[9]*A2.y + y[10]*A2.z + y[11]*A2.w \
        + y[12]*A3.x + y[13]*A3.y + y[14]*A3.z + y[15]*A3.w; \
    o1 += y[0]*B0.x + y[1]*B0.y + y[2]*B0.z + y[3]*B0.w \
        + y[4]*B1.x + y[5]*B1.y + y[6]*B1.z + y[7]*B1.w \
        + y[8]*B2.x + y[9]*B2.y + y[10]*B2.z + y[11]*B2.w \
        + y[12]*B3.x + y[13]*B3.y + y[14]*B3.z + y[15]*B3.w; }

__global__ __launch_bounds__(256) void k_attn(
    const float* __restrict__ Kb, const float* __restrict__ Qb, const float* __restrict__ Vb,
    const float* __restrict__ Ratt,   // [R][H][16][16] (layer slice)
    const float* __restrict__ rmT,    // [R][H][f][d]   (layer slice, transposed)
    const float* __restrict__ pri,    // [R][H]
    const int* __restrict__ off, const int* __restrict__ epk,
    float* __restrict__ agg)
{
    const int wid = threadIdx.x >> 6;
    const int n = blockIdx.x*4 + wid;
    if (n >= N_NODES) return;
    const int lane = threadIdx.x & 63;
    const int h = lane >> 3;
    const int d0 = (lane & 7) * 2;

    // load this head's q
    const float* qp = Qb + (size_t)n*HID + h*DKK;
    float qv[16];
#pragma unroll
    for (int u = 0; u < 4; ++u){
        float4 tq = *(const float4*)(qp + 4*u);
        qv[4*u+0] = tq.x; qv[4*u+1] = tq.y; qv[4*u+2] = tq.z; qv[4*u+3] = tq.w;
    }

    // q~[r][d0..d0+1] = (Ratt[r,h] row-dot q) * pri * 1/sqrt(DK)
    float qtA0, qtA1, qtA2, qtA3, qtB0, qtB1, qtB2, qtB3;
#pragma unroll
    for (int r = 0; r < RR; ++r){
        const float* ar = Ratt + (((size_t)(r*HH + h))*DKK + d0)*DKK;
        float s0 = 0.f, s1 = 0.f;
#pragma unroll
        for (int u = 0; u < 4; ++u){
            float4 a0 = *(const float4*)(ar + 4*u);
            float4 a1 = *(const float4*)(ar + DKK + 4*u);
            s0 += a0.x*qv[4*u+0] + a0.y*qv[4*u+1] + a0.z*qv[4*u+2] + a0.w*qv[4*u+3];
            s1 += a1.x*qv[4*u+0] + a1.y*qv[4*u+1] + a1.z*qv[4*u+2] + a1.w*qv[4*u+3];
        }
        float pr = pri[r*HH + h] * 0.25f; // INV_SQRT_DK
        s0 *= pr; s1 *= pr;
        if      (r == 0){ qtA0 = s0; qtB0 = s1; }
        else if (r == 1){ qtA1 = s0; qtB1 = s1; }
        else if (r == 2){ qtA2 = s0; qtB2 = s1; }
        else            { qtA3 = s0; qtB3 = s1; }
    }

    float m = -INFINITY, l = 0.f;
    float aA0=0.f,aA1=0.f,aA2=0.f,aA3=0.f,aB0=0.f,aB1=0.f,aB2=0.f,aB3=0.f;
    int p = off[n];
    const int p1 = off[n+1];

    for (; p + 4 <= p1; p += 4){
        int pk0 = epk[p+0], pk1 = epk[p+1], pk2 = epk[p+2], pk3 = epk[p+3];
        int s0 = pk0 & 0xFFFF, s1 = pk1 & 0xFFFF, s2 = pk2 & 0xFFFF, s3 = pk3 & 0xFFFF;
        float2 k20 = *(const float2*)(Kb + (size_t)s0*HID + h*DKK + d0);
        float2 k21 = *(const float2*)(Kb + (size_t)s1*HID + h*DKK + d0);
        float2 k22 = *(const float2*)(Kb + (size_t)s2*HID + h*DKK + d0);
        float2 k23 = *(const float2*)(Kb + (size_t)s3*HID + h*DKK + d0);
        float2 v20 = *(const float2*)(Vb + (size_t)s0*HID + h*DKK + d0);
        float2 v21 = *(const float2*)(Vb + (size_t)s1*HID + h*DKK + d0);
        float2 v22 = *(const float2*)(Vb + (size_t)s2*HID + h*DKK + d0);
        float2 v23 = *(const float2*)(Vb + (size_t)s3*HID + h*DKK + d0);
        EDGE_UPDATE(pk0, k20, v20)
        EDGE_UPDATE(pk1, k21, v21)
        EDGE_UPDATE(pk2, k22, v22)
        EDGE_UPDATE(pk3, k23, v23)
    }
    for (; p < p1; ++p){
        int pk = epk[p];
        int s = pk & 0xFFFF;
        float2 k2 = *(const float2*)(Kb + (size_t)s*HID + h*DKK + d0);
        float2 v2 = *(const float2*)(Vb + (size_t)s*HID + h*DKK + d0);
        EDGE_UPDATE(pk, k2, v2)
    }

    const float inv = 1.f / fmaxf(l, 1e-9f);
    float o0 = 0.f, o1 = 0.f;
    FINAL_R(aA0, aB0, 0)
    FINAL_R(aA1, aB1, 1)
    FINAL_R(aA2, aB2, 2)
    FINAL_R(aA3, aB3, 3)
    *(float2*)(agg + (size_t)n*HID + h*DKK + d0) = make_float2(o0*inv, o1*inv);
}

// ---------------- output GEMM: gelu(agg) @ Wa + blend (+LN+ReLU) ----------------

template<bool USE_LN>
__global__ __launch_bounds__(256) void k_out(
    const float* __restrict__ aggb, const float* __restrict__ Wa_, const float* __restrict__ ba_,
    const float* __restrict__ hin, const float* __restrict__ skipl,
    const float* __restrict__ gam, const float* __restrict__ bet,
    const int* __restrict__ nperm, const int* __restrict__ offT, const int* __restrict__ cntT,
    float* __restrict__ hout)
{
    const int t = blockIdx.y;
    const int cnt = cntT[t];
    const int base = blockIdx.x * 64;
    if (base >= cnt) return;
    __shared__ float xs[64][132];
    __shared__ int nid[64];
    const int tid = threadIdx.x;
    if (tid < 64){
        int ii = base + tid;
        nid[tid] = (ii < cnt) ? nperm[offT[t] + ii] : -1;
    }
    __syncthreads();
    const int c0  = (tid & 31) * 4;
    const int rg8 = (tid >> 5) * 8;
    const float* __restrict__ W = Wa_ + (size_t)t*HID*HID;
    float4 acc[8];
#pragma unroll
    for (int r = 0; r < 8; ++r) acc[r] = make_float4(0.f,0.f,0.f,0.f);

    {
        const int kc = 0;
        for (int i = tid; i < 64*32; i += 256){
            int row = i >> 5, k4 = i & 31;
            int node = nid[row];
            float4 val = make_float4(0.f,0.f,0.f,0.f);
            if (node >= 0){
                val = *(const float4*)&aggb[(size_t)node*HID + k4*4];
                val.x = geluf(val.x); val.y = geluf(val.y);
                val.z = geluf(val.z); val.w = geluf(val.w);
            }
            *(float4*)&xs[row][k4*4] = val;
        }
        __syncthreads();
        GEMM_CHUNK(128)
    }
    const float alpha = 1.f / (1.f + __expf(-skipl[t]));
    const float one_m = 1.f - alpha;
    float4 b4 = *(const float4*)&ba_[t*HID + c0];
#pragma unroll
    for (int rr = 0; rr < 8; ++rr){
        int node = nid[rg8 + rr];
        float4 a = acc[rr];
        if (node >= 0){
            float4 xv = *(const float4*)&hin[(size_t)node*HID + c0];
            a.x = (a.x + b4.x)*alpha + xv.x*one_m;
            a.y = (a.y + b4.y)*alpha + xv.y*one_m;
            a.z = (a.z + b4.z)*alpha + xv.z*one_m;
            a.w = (a.w + b4.w)*alpha + xv.w*one_m;
        } else a = make_float4(0.f,0.f,0.f,0.f);
        acc[rr] = a;
    }
    if (USE_LN){
        float4 g4 = *(const float4*)&gam[t*HID + c0];
        float4 e4 = *(const float4*)&bet[t*HID + c0];
#pragma unroll
        for (int rr = 0; rr < 8; ++rr){
            float4 a = acc[rr];
            float s  = a.x + a.y + a.z + a.w;
            float s2 = a.x*a.x + a.y*a.y + a.z*a.z + a.w*a.w;
#pragma unroll
            for (int o = 1; o < 32; o <<= 1){
                s  += __shfl_xor(s,  o);
                s2 += __shfl_xor(s2, o);
            }
            float mu  = s * (1.f/128.f);
            float var = s2 * (1.f/128.f) - mu*mu;
            float rstd = rsqrtf(var + 1e-5f);
            int node = nid[rg8 + rr];
            if (node >= 0){
                float4 r4;
                r4.x = fmaxf((a.x - mu)*rstd*g4.x + e4.x, 0.f);
                r4.y = fmaxf((a.y - mu)*rstd*g4.y + e4.y, 0.f);
                r4.z = fmaxf((a.z - mu)*rstd*g4.z + e4.z, 0.f);
                r4.w = fmaxf((a.w - mu)*rstd*g4.w + e4.w, 0.f);
                *(float4*)&hout[(size_t)node*HID + c0] = r4;
            }
        }
    } else {
#pragma unroll
        for (int rr = 0; rr < 8; ++rr){
            int node = nid[rg8 + rr];
            if (node >= 0)
                *(float4*)&hout[(size_t)node*HID + c0] = acc[rr];
        }
    }
}

// ---------------- launch ----------------

extern "C" void kernel_launch(void* const* d_in, const int* in_sizes, int n_in,
                              void* d_out, int out_size, void* d_ws, size_t ws_size,
                              hipStream_t stream)
{
    const float* x         = (const float*)d_in[0];
    const int*   node_types= (const int*)  d_in[1];
    const int*   edge_index= (const int*)  d_in[2];
    const int*   edge_types= (const int*)  d_in[3];
    const float* W_adapt   = (const float*)d_in[4];
    const float* b_adapt   = (const float*)d_in[5];
    const float* Wk        = (const float*)d_in[6];
    const float* bk        = (const float*)d_in[7];
    const float* Wq        = (const float*)d_in[8];
    const float* bq        = (const float*)d_in[9];
    const float* Wv        = (const float*)d_in[10];
    const float* bv        = (const float*)d_in[11];
    const float* Wa        = (const float*)d_in[12];
    const float* ba        = (const float*)d_in[13];
    const float* rel_pri   = (const float*)d_in[14];
    const float* rel_att   = (const float*)d_in[15];
    const float* rel_msg   = (const float*)d_in[16];
    const float* skip      = (const float*)d_in[17];
    const float* ln_g      = (const float*)d_in[18];
    const float* ln_b      = (const float*)d_in[19];
    float* out = (float*)d_out;

    char* p = (char*)d_ws;
    auto alloc = [&](size_t bytes) -> void* {
        void* q = (void*)p;
        p += (bytes + 255) & ~(size_t)255;
        return q;
    };
    float* h0   = (float*)alloc((size_t)N_NODES*HID*4);
    float* Kb   = (float*)alloc((size_t)N_NODES*HID*4);
    float* Qb   = (float*)alloc((size_t)N_NODES*HID*4);
    float* Vb   = (float*)alloc((size_t)N_NODES*HID*4);
    float* aggb = (float*)alloc((size_t)N_NODES*HID*4);
    float* rmT  = (float*)alloc((size_t)2*RR*HH*DKK*DKK*4);
    int* ib     = (int*)alloc((size_t)(2*N_NODES + 8)*4);
    int* deg  = ib;
    int* tmpN = ib + N_NODES;
    int* cntT = ib + 2*N_NODES;
    int* tmpT = ib + 2*N_NODES + 4;
    int* off   = (int*)alloc((size_t)(N_NODES+1)*4);
    int* offT  = (int*)alloc(16);
    int* epk   = (int*)alloc((size_t)E_EDGES*4);
    int* nperm = (int*)alloc((size_t)N_NODES*4);

    const int* esrc = edge_index;
    const int* edst = edge_index + E_EDGES;

    hipMemsetAsync(ib, 0, (size_t)(2*N_NODES + 8)*4, stream);
    k_hist_nodes<<<(N_NODES+255)/256, 256, 0, stream>>>(node_types, cntT, N_NODES);
    k_hist_edges<<<(E_EDGES+255)/256, 256, 0, stream>>>(edst, deg, E_EDGES);
    k_offT<<<1, 1, 0, stream>>>(cntT, offT);
    k_scan<<<1, 1024, 0, stream>>>(deg, off, N_NODES);
    k_scatter_nodes<<<(N_NODES+255)/256, 256, 0, stream>>>(node_types, offT, tmpT, nperm, N_NODES);
    k_scatter_edges<<<(E_EDGES+255)/256, 256, 0, stream>>>(esrc, edst, edge_types, off, tmpN, epk, E_EDGES);
    k_transpose_rmsg<<<(2*RR*HH*DKK*DKK+255)/256, 256, 0, stream>>>(rel_msg, rmT);

    dim3 gg((N_NODES+63)/64, TT);
    k_adapt<<<gg, 256, 0, stream>>>(x, W_adapt, b_adapt, nperm, offT, cntT, h0);

    for (int l = 0; l < 2; ++l){
        const float* hin = (l == 0) ? h0 : out;
        const size_t WOFF = (size_t)l*TT*HID*HID;
        const size_t BOFF = (size_t)l*TT*HID;
        dim3 g3((N_NODES+63)/64, TT, 3);
        k_kqv<<<g3, 256, 0, stream>>>(hin, Wk+WOFF, bk+BOFF, Wq+WOFF, bq+BOFF, Wv+WOFF, bv+BOFF,
                                      nperm, offT, cntT, Kb, Qb, Vb);
        k_attn<<<(N_NODES+3)/4, 256, 0, stream>>>(Kb, Qb, Vb,
            rel_att + (size_t)l*RR*HH*DKK*DKK,
            rmT + (size_t)l*RR*HH*DKK*DKK,
            rel_pri + (size_t)l*RR*HH,
            off, epk, aggb);
        if (l == 0)
            k_out<true><<<gg, 256, 0, stream>>>(aggb, Wa+WOFF, ba+BOFF, hin, skip + l*TT,
                                                ln_g, ln_b, nperm, offT, cntT, out);
        else
            k_out<false><<<gg, 256, 0, stream>>>(aggb, Wa+WOFF, ba+BOFF, hin, skip + l*TT,
                                                 ln_g, ln_b, nperm, offT, cntT, out);
    }
}

// Round 3
// 1825.912 us; speedup vs baseline: 1.4186x; 1.0939x over previous
//
#include <hip/hip_runtime.h>
#include <math.h>

#define N_NODES 50000
#define E_EDGES 400000
#define IN_DIM  256
#define HID     128
#define TT      3
#define RR      4
#define HH      8
#define DKK     16

__device__ __forceinline__ float geluf(float v){
    return 0.5f * v * (1.f + erff(v * 0.70710678118654752440f));
}

// ---------------- setup kernels ----------------

__global__ void k_hist_nodes(const int* __restrict__ nt, int* __restrict__ cntT, int n){
    int i = blockIdx.x*blockDim.x + threadIdx.x;
    if (i < n) atomicAdd(&cntT[nt[i]], 1);
}

__global__ void k_hist_edges(const int* __restrict__ edst, int* __restrict__ deg, int e){
    int i = blockIdx.x*blockDim.x + threadIdx.x;
    if (i < e) atomicAdd(&deg[edst[i]], 1);
}

__global__ void k_offT(const int* __restrict__ cntT, int* __restrict__ offT){
    if (threadIdx.x == 0 && blockIdx.x == 0){
        int a = 0;
        for (int t = 0; t < TT; ++t){ offT[t] = a; a += cntT[t]; }
        offT[TT] = a;
    }
}

__global__ void k_scatter_nodes(const int* __restrict__ nt, const int* __restrict__ offT,
                                int* __restrict__ tmpT, int* __restrict__ nperm, int n){
    int i = blockIdx.x*blockDim.x + threadIdx.x;
    if (i < n){
        int t = nt[i];
        int p = offT[t] + atomicAdd(&tmpT[t], 1);
        nperm[p] = i;
    }
}

__global__ void k_scan(const int* __restrict__ deg, int* __restrict__ off, int n){
    __shared__ int sums[1024];
    int tid = threadIdx.x;
    int chunk = (n + 1023) >> 10;
    int st = tid*chunk, en = st + chunk; if (en > n) en = n;
    int s = 0;
    for (int i = st; i < en; ++i) s += deg[i];
    sums[tid] = s;
    __syncthreads();
    for (int o = 1; o < 1024; o <<= 1){
        int v = (tid >= o) ? sums[tid-o] : 0;
        __syncthreads();
        sums[tid] += v;
        __syncthreads();
    }
    int run = (tid == 0) ? 0 : sums[tid-1];
    for (int i = st; i < en; ++i){ off[i] = run; run += deg[i]; }
    if (tid == 1023) off[n] = run;
}

// sorted packed edges: epk[p] = src | (type<<16)
__global__ void k_scatter_edges(const int* __restrict__ esrc, const int* __restrict__ edst,
                                const int* __restrict__ ety,
                                const int* __restrict__ off, int* __restrict__ tmpN,
                                int* __restrict__ epk, int e){
    int i = blockIdx.x*blockDim.x + threadIdx.x;
    if (i < e){
        int d = edst[i];
        int p = off[d] + atomicAdd(&tmpN[d], 1);
        epk[p] = esrc[i] | (ety[i] << 16);
    }
}

// rel_msg [2][R][H][d][f] -> rmT [2][R][H][f][d]
__global__ void k_transpose_rmsg(const float* __restrict__ rm, float* __restrict__ rmT){
    int i = blockIdx.x*blockDim.x + threadIdx.x;
    const int tot = 2*RR*HH*DKK*DKK;
    if (i < tot){
        int f = i & 15;
        int d = (i >> 4) & 15;
        int rest = i >> 8;
        rmT[(rest*DKK + f)*DKK + d] = rm[i];
    }
}

// ---------------- register-blocked GEMM chunk ----------------
// block 64 rows x 128 cols, 256 threads; thread 8 rows x 4 cols.

#define GEMM_CHUNK(BK) \
  _Pragma("unroll 2") \
  for (int k = 0; k < (BK); k += 4){ \
    float4 w0 = *(const float4*)&W[(size_t)(kc + k + 0)*HID + c0]; \
    float4 w1 = *(const float4*)&W[(size_t)(kc + k + 1)*HID + c0]; \
    float4 w2 = *(const float4*)&W[(size_t)(kc + k + 2)*HID + c0]; \
    float4 w3 = *(const float4*)&W[(size_t)(kc + k + 3)*HID + c0]; \
    _Pragma("unroll") \
    for (int rr = 0; rr < 8; ++rr){ \
      float4 xv = *(const float4*)&xs[rg8 + rr][k]; \
      float4 a = acc[rr]; \
      a.x = fmaf(xv.x, w0.x, a.x); a.y = fmaf(xv.x, w0.y, a.y); a.z = fmaf(xv.x, w0.z, a.z); a.w = fmaf(xv.x, w0.w, a.w); \
      a.x = fmaf(xv.y, w1.x, a.x); a.y = fmaf(xv.y, w1.y, a.y); a.z = fmaf(xv.y, w1.z, a.z); a.w = fmaf(xv.y, w1.w, a.w); \
      a.x = fmaf(xv.z, w2.x, a.x); a.y = fmaf(xv.z, w2.y, a.y); a.z = fmaf(xv.z, w2.z, a.z); a.w = fmaf(xv.z, w2.w, a.w); \
      a.x = fmaf(xv.w, w3.x, a.x); a.y = fmaf(xv.w, w3.y, a.y); a.z = fmaf(xv.w, w3.z, a.z); a.w = fmaf(xv.w, w3.w, a.w); \
      acc[rr] = a; \
    } \
  }

// ---------------- adapt: h0 = tanh(x @ W_adapt[t] + b), K=256 ----------------

__global__ __launch_bounds__(256) void k_adapt(
    const float* __restrict__ x, const float* __restrict__ W_, const float* __restrict__ b_,
    const int* __restrict__ nperm, const int* __restrict__ offT, const int* __restrict__ cntT,
    float* __restrict__ h0)
{
    const int t = blockIdx.y;
    const int cnt = cntT[t];
    const int base = blockIdx.x * 64;
    if (base >= cnt) return;
    __shared__ float xs[64][132];
    __shared__ int nid[64];
    const int tid = threadIdx.x;
    if (tid < 64){
        int ii = base + tid;
        nid[tid] = (ii < cnt) ? nperm[offT[t] + ii] : -1;
    }
    __syncthreads();
    const int c0  = (tid & 31) * 4;
    const int rg8 = (tid >> 5) * 8;
    const float* __restrict__ W = W_ + (size_t)t*IN_DIM*HID;
    float4 acc[8];
#pragma unroll
    for (int r = 0; r < 8; ++r) acc[r] = make_float4(0.f,0.f,0.f,0.f);

    for (int kc = 0; kc < IN_DIM; kc += 128){
        for (int i = tid; i < 64*32; i += 256){
            int row = i >> 5, k4 = i & 31;
            int node = nid[row];
            float4 val = make_float4(0.f,0.f,0.f,0.f);
            if (node >= 0) val = *(const float4*)&x[(size_t)node*IN_DIM + kc + k4*4];
            *(float4*)&xs[row][k4*4] = val;
        }
        __syncthreads();
        GEMM_CHUNK(128)
        __syncthreads();
    }
    float4 b4 = *(const float4*)&b_[t*HID + c0];
#pragma unroll
    for (int rr = 0; rr < 8; ++rr){
        int node = nid[rg8 + rr];
        if (node >= 0){
            float4 a = acc[rr];
            a.x = tanhf(a.x + b4.x); a.y = tanhf(a.y + b4.y);
            a.z = tanhf(a.z + b4.z); a.w = tanhf(a.w + b4.w);
            *(float4*)&h0[(size_t)node*HID + c0] = a;
        }
    }
}

// ---------------- merged K/Q/V GEMM; K,V written packed-interleaved ----------------
// KVp float2 layout: slot (node,h,jj) -> KVp2[(node*64 + h*8 + jj)*2 + {0=K,1=V}]

#define PASS(WSEL, BSEL, STORE) { \
    const float* __restrict__ W = (WSEL) + (size_t)t*HID*HID; \
    float4 acc[8]; \
    _Pragma("unroll") \
    for (int r = 0; r < 8; ++r) acc[r] = make_float4(0.f,0.f,0.f,0.f); \
    const int kc = 0; \
    GEMM_CHUNK(128) \
    float4 b4 = *(const float4*)&(BSEL)[t*HID + c0]; \
    _Pragma("unroll") \
    for (int rr = 0; rr < 8; ++rr){ \
        int node = nid[rg8 + rr]; \
        if (node >= 0){ \
            float4 a = acc[rr]; \
            a.x += b4.x; a.y += b4.y; a.z += b4.z; a.w += b4.w; \
            STORE \
        } \
    } }

__global__ __launch_bounds__(256) void k_kqv(
    const float* __restrict__ h,
    const float* __restrict__ Wk_, const float* __restrict__ bk_,
    const float* __restrict__ Wq_, const float* __restrict__ bq_,
    const float* __restrict__ Wv_, const float* __restrict__ bv_,
    const int* __restrict__ nperm, const int* __restrict__ offT, const int* __restrict__ cntT,
    float* __restrict__ Qb, float2* __restrict__ KVp2)
{
    const int t = blockIdx.y;
    const int cnt = cntT[t];
    const int base = blockIdx.x * 64;
    if (base >= cnt) return;
    __shared__ float xs[64][132];
    __shared__ int nid[64];
    const int tid = threadIdx.x;
    if (tid < 64){
        int ii = base + tid;
        nid[tid] = (ii < cnt) ? nperm[offT[t] + ii] : -1;
    }
    __syncthreads();
    const int c0  = (tid & 31) * 4;
    const int rg8 = (tid >> 5) * 8;
    // stage input rows once, reuse for K,Q,V
    for (int i = tid; i < 64*32; i += 256){
        int row = i >> 5, k4 = i & 31;
        int node = nid[row];
        float4 val = make_float4(0.f,0.f,0.f,0.f);
        if (node >= 0) val = *(const float4*)&h[(size_t)node*HID + k4*4];
        *(float4*)&xs[row][k4*4] = val;
    }
    __syncthreads();
    const int hh  = c0 >> 4;
    const int jj0 = (c0 & 15) >> 1;
    PASS(Wk_, bk_, {
        float2* bp = KVp2 + (((size_t)node << 6) + hh*8 + jj0)*2;
        bp[0] = make_float2(a.x, a.y);
        bp[2] = make_float2(a.z, a.w);
    })
    PASS(Wq_, bq_, {
        *(float4*)&Qb[(size_t)node*HID + c0] = a;
    })
    PASS(Wv_, bv_, {
        float2* bp = KVp2 + (((size_t)node << 6) + hh*8 + jj0)*2;
        bp[1] = make_float2(a.x, a.y);
        bp[3] = make_float2(a.z, a.w);
    })
}

// ---------------- per-node attention v3 ----------------
// wave handles 2 nodes; lane = h*8+jj owns dims 2jj,2jj+1 of head h; slot==lane.
// batched (4-edge) online softmax: one rescale per batch; deferred Rmsg at end.

#define LOADKV4(S, P) \
    int pk##S##0 = epk[(P)+0], pk##S##1 = epk[(P)+1], pk##S##2 = epk[(P)+2], pk##S##3 = epk[(P)+3]; \
    float4 kv##S##0 = KVp[(size_t)(pk##S##0 & 0xFFFF)*64 + lane]; \
    float4 kv##S##1 = KVp[(size_t)(pk##S##1 & 0xFFFF)*64 + lane]; \
    float4 kv##S##2 = KVp[(size_t)(pk##S##2 & 0xFFFF)*64 + lane]; \
    float4 kv##S##3 = KVp[(size_t)(pk##S##3 & 0xFFFF)*64 + lane];

#define LOGIT_I(S, i) \
    float part##S##i; { \
        int r_ = pk##S##i >> 16; \
        float qa_ = (r_==0)?qa0##S:(r_==1)?qa1##S:(r_==2)?qa2##S:qa3##S; \
        float qb_ = (r_==0)?qb0##S:(r_==1)?qb1##S:(r_==2)?qb2##S:qb3##S; \
        part##S##i = fmaf(kv##S##i.x, qa_, kv##S##i.y * qb_); \
    } \
    part##S##i += __shfl_xor(part##S##i, 1); \
    part##S##i += __shfl_xor(part##S##i, 2); \
    part##S##i += __shfl_xor(part##S##i, 4);

#define ACC_I(S, i) { \
    int r_ = pk##S##i >> 16; \
    float e_ = __expf(part##S##i - mn##S); \
    l##S += e_; \
    float w0_=(r_==0)?e_:0.f, w1_=(r_==1)?e_:0.f, w2_=(r_==2)?e_:0.f, w3_=(r_==3)?e_:0.f; \
    cx0##S = fmaf(w0_, kv##S##i.z, cx0##S); cy0##S = fmaf(w0_, kv##S##i.w, cy0##S); \
    cx1##S = fmaf(w1_, kv##S##i.z, cx1##S); cy1##S = fmaf(w1_, kv##S##i.w, cy1##S); \
    cx2##S = fmaf(w2_, kv##S##i.z, cx2##S); cy2##S = fmaf(w2_, kv##S##i.w, cy2##S); \
    cx3##S = fmaf(w3_, kv##S##i.z, cx3##S); cy3##S = fmaf(w3_, kv##S##i.w, cy3##S); }

#define BATCH4(S) \
    LOGIT_I(S,0) LOGIT_I(S,1) LOGIT_I(S,2) LOGIT_I(S,3) \
    float bm##S = fmaxf(fmaxf(part##S##0, part##S##1), fmaxf(part##S##2, part##S##3)); \
    float mn##S = fmaxf(m##S, bm##S); \
    float sc##S = __expf(m##S - mn##S); \
    m##S = mn##S; l##S *= sc##S; \
    cx0##S *= sc##S; cx1##S *= sc##S; cx2##S *= sc##S; cx3##S *= sc##S; \
    cy0##S *= sc##S; cy1##S *= sc##S; cy2##S *= sc##S; cy3##S *= sc##S; \
    ACC_I(S,0) ACC_I(S,1) ACC_I(S,2) ACC_I(S,3)

#define TAIL4(S, P, P1) { \
    int pk##S##0 = epk[P]; \
    int pk##S##1 = epk[((P)+1 < (P1)) ? (P)+1 : (P1)-1]; \
    int pk##S##2 = epk[((P)+2 < (P1)) ? (P)+2 : (P1)-1]; \
    int pk##S##3 = epk[((P)+3 < (P1)) ? (P)+3 : (P1)-1]; \
    float4 kv##S##0 = KVp[(size_t)(pk##S##0 & 0xFFFF)*64 + lane]; \
    float4 kv##S##1 = KVp[(size_t)(pk##S##1 & 0xFFFF)*64 + lane]; \
    float4 kv##S##2 = KVp[(size_t)(pk##S##2 & 0xFFFF)*64 + lane]; \
    float4 kv##S##3 = KVp[(size_t)(pk##S##3 & 0xFFFF)*64 + lane]; \
    LOGIT_I(S,0) LOGIT_I(S,1) LOGIT_I(S,2) LOGIT_I(S,3) \
    if ((P)+1 >= (P1)) part##S##1 = -INFINITY; \
    if ((P)+2 >= (P1)) part##S##2 = -INFINITY; \
    if ((P)+3 >= (P1)) part##S##3 = -INFINITY; \
    float bm##S = fmaxf(fmaxf(part##S##0, part##S##1), fmaxf(part##S##2, part##S##3)); \
    float mn##S = fmaxf(m##S, bm##S); \
    float sc##S = __expf(m##S - mn##S); \
    m##S = mn##S; l##S *= sc##S; \
    cx0##S *= sc##S; cx1##S *= sc##S; cx2##S *= sc##S; cx3##S *= sc##S; \
    cy0##S *= sc##S; cy1##S *= sc##S; cy2##S *= sc##S; cy3##S *= sc##S; \
    ACC_I(S,0) ACC_I(S,1) ACC_I(S,2) ACC_I(S,3) }

#define FINAL2(RIDX) { \
    const float* rm = rmT + (((size_t)((RIDX)*HH + h))*DKK + d0)*DKK; \
    float4 A0 = *(const float4*)(rm + 0),  A1 = *(const float4*)(rm + 4); \
    float4 A2 = *(const float4*)(rm + 8),  A3 = *(const float4*)(rm + 12); \
    float4 B0 = *(const float4*)(rm + 16), B1 = *(const float4*)(rm + 20); \
    float4 B2 = *(const float4*)(rm + 24), B3 = *(const float4*)(rm + 28); \
    float yA[16], yB[16]; \
    _Pragma("unroll") \
    for (int u = 0; u < 8; ++u){ \
        yA[2*u]   = __shfl(cx##RIDX##A, (h<<3) + u); \
        yA[2*u+1] = __shfl(cy##RIDX##A, (h<<3) + u); \
        yB[2*u]   = __shfl(cx##RIDX##B, (h<<3) + u); \
        yB[2*u+1] = __shfl(cy##RIDX##B, (h<<3) + u); \
    } \
    o0A += yA[0]*A0.x + yA[1]*A0.y + yA[2]*A0.z + yA[3]*A0.w \
         + yA[4]*A1.x + yA[5]*A1.y + yA[6]*A1.z + yA[7]*A1.w \
         + yA[8]*A2.x + yA[9]*A2.y + yA[10]*A2.z + yA[11]*A2.w \
         + yA[12]*A3.x + yA[13]*A3.y + yA[14]*A3.z + yA[15]*A3.w; \
    o1A += yA[0]*B0.x + yA[1]*B0.y + yA[2]*B0.z + yA[3]*B0.w \
         + yA[4]*B1.x + yA[5]*B1.y + yA[6]*B1.z + yA[7]*B1.w \
         + yA[8]*B2.x + yA[9]*B2.y + yA[10]*B2.z + yA[11]*B2.w \
         + yA[12]*B3.x + yA[13]*B3.y + yA[14]*B3.z + yA[15]*B3.w; \
    o0B += yB[0]*A0.x + yB[1]*A0.y + yB[2]*A0.z + yB[3]*A0.w \
         + yB[4]*A1.x + yB[5]*A1.y + yB[6]*A1.z + yB[7]*A1.w \
         + yB[8]*A2.x + yB[9]*A2.y + yB[10]*A2.z + yB[11]*A2.w \
         + yB[12]*A3.x + yB[13]*A3.y + yB[14]*A3.z + yB[15]*A3.w; \
    o1B += yB[0]*B0.x + yB[1]*B0.y + yB[2]*B0.z + yB[3]*B0.w \
         + yB[4]*B1.x + yB[5]*B1.y + yB[6]*B1.z + yB[7]*B1.w \
         + yB[8]*B2.x + yB[9]*B2.y + yB[10]*B2.z + yB[11]*B2.w \
         + yB[12]*B3.x + yB[13]*B3.y + yB[14]*B3.z + yB[15]*B3.w; }

__global__ __launch_bounds__(256) void k_attn(
    const float* __restrict__ Qb, const float4* __restrict__ KVp,
    const float* __restrict__ Ratt, const float* __restrict__ rmT,
    const float* __restrict__ pri,
    const int* __restrict__ off, const int* __restrict__ epk,
    float* __restrict__ agg)
{
    const int wid = threadIdx.x >> 6;
    const int n0 = blockIdx.x*8 + wid*2;
    if (n0 >= N_NODES) return;
    const bool hasB = (n0 + 1) < N_NODES;
    const int lane = threadIdx.x & 63;
    const int h  = lane >> 3;
    const int d0 = (lane & 7) * 2;

    // load q for both nodes
    const float* qpA = Qb + (size_t)n0*HID + h*DKK;
    const float* qpB = Qb + (size_t)(hasB ? n0+1 : n0)*HID + h*DKK;
    float qvA[16], qvB[16];
#pragma unroll
    for (int u = 0; u < 4; ++u){
        float4 ta = *(const float4*)(qpA + 4*u);
        float4 tb = *(const float4*)(qpB + 4*u);
        qvA[4*u+0]=ta.x; qvA[4*u+1]=ta.y; qvA[4*u+2]=ta.z; qvA[4*u+3]=ta.w;
        qvB[4*u+0]=tb.x; qvB[4*u+1]=tb.y; qvB[4*u+2]=tb.z; qvB[4*u+3]=tb.w;
    }

    // q~ per relation (rows d0, d0+1), shared Ratt loads for both nodes
    float qa0A,qa1A,qa2A,qa3A,qb0A,qb1A,qb2A,qb3A;
    float qa0B,qa1B,qa2B,qa3B,qb0B,qb1B,qb2B,qb3B;
#pragma unroll
    for (int r = 0; r < RR; ++r){
        const float* ar = Ratt + (((size_t)(r*HH + h))*DKK + d0)*DKK;
        float s0A=0.f, s1A=0.f, s0B=0.f, s1B=0.f;
#pragma unroll
        for (int u = 0; u < 4; ++u){
            float4 a0 = *(const float4*)(ar + 4*u);
            float4 a1 = *(const float4*)(ar + DKK + 4*u);
            s0A += a0.x*qvA[4*u+0] + a0.y*qvA[4*u+1] + a0.z*qvA[4*u+2] + a0.w*qvA[4*u+3];
            s1A += a1.x*qvA[4*u+0] + a1.y*qvA[4*u+1] + a1.z*qvA[4*u+2] + a1.w*qvA[4*u+3];
            s0B += a0.x*qvB[4*u+0] + a0.y*qvB[4*u+1] + a0.z*qvB[4*u+2] + a0.w*qvB[4*u+3];
            s1B += a1.x*qvB[4*u+0] + a1.y*qvB[4*u+1] + a1.z*qvB[4*u+2] + a1.w*qvB[4*u+3];
        }
        float pr = pri[r*HH + h] * 0.25f;
        s0A *= pr; s1A *= pr; s0B *= pr; s1B *= pr;
        if      (r == 0){ qa0A=s0A; qb0A=s1A; qa0B=s0B; qb0B=s1B; }
        else if (r == 1){ qa1A=s0A; qb1A=s1A; qa1B=s0B; qb1B=s1B; }
        else if (r == 2){ qa2A=s0A; qb2A=s1A; qa2B=s0B; qb2B=s1B; }
        else            { qa3A=s0A; qb3A=s1A; qa3B=s0B; qb3B=s1B; }
    }

    float mA=-INFINITY, lA=0.f, cx0A=0.f,cx1A=0.f,cx2A=0.f,cx3A=0.f, cy0A=0.f,cy1A=0.f,cy2A=0.f,cy3A=0.f;
    float mB=-INFINITY, lB=0.f, cx0B=0.f,cx1B=0.f,cx2B=0.f,cx3B=0.f, cy0B=0.f,cy1B=0.f,cy2B=0.f,cy3B=0.f;

    int pa = off[n0],  ea = off[n0+1];
    int pb = 0, eb = 0;
    if (hasB){ pb = ea; eb = off[n0+2]; }

    // dual main loop: 8 gathers in flight, 2 independent softmax chains
    while (pa + 4 <= ea && pb + 4 <= eb){
        LOADKV4(A, pa)
        LOADKV4(B, pb)
        BATCH4(A)
        BATCH4(B)
        pa += 4; pb += 4;
    }
    while (pa + 4 <= ea){
        LOADKV4(A, pa)
        BATCH4(A)
        pa += 4;
    }
    while (pb + 4 <= eb){
        LOADKV4(B, pb)
        BATCH4(B)
        pb += 4;
    }
    if (pa < ea) TAIL4(A, pa, ea)
    if (pb < eb) TAIL4(B, pb, eb)

    // apply Rmsg once per node (deferred), both nodes share rm loads
    float o0A=0.f, o1A=0.f, o0B=0.f, o1B=0.f;
    FINAL2(0)
    FINAL2(1)
    FINAL2(2)
    FINAL2(3)

    const float invA = 1.f / fmaxf(lA, 1e-9f);
    *(float2*)(agg + (size_t)n0*HID + h*DKK + d0) = make_float2(o0A*invA, o1A*invA);
    if (hasB){
        const float invB = 1.f / fmaxf(lB, 1e-9f);
        *(float2*)(agg + (size_t)(n0+1)*HID + h*DKK + d0) = make_float2(o0B*invB, o1B*invB);
    }
}

// ---------------- output GEMM: gelu(agg) @ Wa + blend (+LN+ReLU) ----------------

template<bool USE_LN>
__global__ __launch_bounds__(256) void k_out(
    const float* __restrict__ aggb, const float* __restrict__ Wa_, const float* __restrict__ ba_,
    const float* __restrict__ hin, const float* __restrict__ skipl,
    const float* __restrict__ gam, const float* __restrict__ bet,
    const int* __restrict__ nperm, const int* __restrict__ offT, const int* __restrict__ cntT,
    float* __restrict__ hout)
{
    const int t = blockIdx.y;
    const int cnt = cntT[t];
    const int base = blockIdx.x * 64;
    if (base >= cnt) return;
    __shared__ float xs[64][132];
    __shared__ int nid[64];
    const int tid = threadIdx.x;
    if (tid < 64){
        int ii = base + tid;
        nid[tid] = (ii < cnt) ? nperm[offT[t] + ii] : -1;
    }
    __syncthreads();
    const int c0  = (tid & 31) * 4;
    const int rg8 = (tid >> 5) * 8;
    const float* __restrict__ W = Wa_ + (size_t)t*HID*HID;
    float4 acc[8];
#pragma unroll
    for (int r = 0; r < 8; ++r) acc[r] = make_float4(0.f,0.f,0.f,0.f);

    {
        const int kc = 0;
        for (int i = tid; i < 64*32; i += 256){
            int row = i >> 5, k4 = i & 31;
            int node = nid[row];
            float4 val = make_float4(0.f,0.f,0.f,0.f);
            if (node >= 0){
                val = *(const float4*)&aggb[(size_t)node*HID + k4*4];
                val.x = geluf(val.x); val.y = geluf(val.y);
                val.z = geluf(val.z); val.w = geluf(val.w);
            }
            *(float4*)&xs[row][k4*4] = val;
        }
        __syncthreads();
        GEMM_CHUNK(128)
    }
    const float alpha = 1.f / (1.f + __expf(-skipl[t]));
    const float one_m = 1.f - alpha;
    float4 b4 = *(const float4*)&ba_[t*HID + c0];
#pragma unroll
    for (int rr = 0; rr < 8; ++rr){
        int node = nid[rg8 + rr];
        float4 a = acc[rr];
        if (node >= 0){
            float4 xv = *(const float4*)&hin[(size_t)node*HID + c0];
            a.x = (a.x + b4.x)*alpha + xv.x*one_m;
            a.y = (a.y + b4.y)*alpha + xv.y*one_m;
            a.z = (a.z + b4.z)*alpha + xv.z*one_m;
            a.w = (a.w + b4.w)*alpha + xv.w*one_m;
        } else a = make_float4(0.f,0.f,0.f,0.f);
        acc[rr] = a;
    }
    if (USE_LN){
        float4 g4 = *(const float4*)&gam[t*HID + c0];
        float4 e4 = *(const float4*)&bet[t*HID + c0];
#pragma unroll
        for (int rr = 0; rr < 8; ++rr){
            float4 a = acc[rr];
            float s  = a.x + a.y + a.z + a.w;
            float s2 = a.x*a.x + a.y*a.y + a.z*a.z + a.w*a.w;
#pragma unroll
            for (int o = 1; o < 32; o <<= 1){
                s  += __shfl_xor(s,  o);
                s2 += __shfl_xor(s2, o);
            }
            float mu  = s * (1.f/128.f);
            float var = s2 * (1.f/128.f) - mu*mu;
            float rstd = rsqrtf(var + 1e-5f);
            int node = nid[rg8 + rr];
            if (node >= 0){
                float4 r4;
                r4.x = fmaxf((a.x - mu)*rstd*g4.x + e4.x, 0.f);
                r4.y = fmaxf((a.y - mu)*rstd*g4.y + e4.y, 0.f);
                r4.z = fmaxf((a.z - mu)*rstd*g4.z + e4.z, 0.f);
                r4.w = fmaxf((a.w - mu)*rstd*g4.w + e4.w, 0.f);
                *(float4*)&hout[(size_t)node*HID + c0] = r4;
            }
        }
    } else {
#pragma unroll
        for (int rr = 0; rr < 8; ++rr){
            int node = nid[rg8 + rr];
            if (node >= 0)
                *(float4*)&hout[(size_t)node*HID + c0] = acc[rr];
        }
    }
}

// ---------------- launch ----------------

extern "C" void kernel_launch(void* const* d_in, const int* in_sizes, int n_in,
                              void* d_out, int out_size, void* d_ws, size_t ws_size,
                              hipStream_t stream)
{
    const float* x         = (const float*)d_in[0];
    const int*   node_types= (const int*)  d_in[1];
    const int*   edge_index= (const int*)  d_in[2];
    const int*   edge_types= (const int*)  d_in[3];
    const float* W_adapt   = (const float*)d_in[4];
    const float* b_adapt   = (const float*)d_in[5];
    const float* Wk        = (const float*)d_in[6];
    const float* bk        = (const float*)d_in[7];
    const float* Wq        = (const float*)d_in[8];
    const float* bq        = (const float*)d_in[9];
    const float* Wv        = (const float*)d_in[10];
    const float* bv        = (const float*)d_in[11];
    const float* Wa        = (const float*)d_in[12];
    const float* ba        = (const float*)d_in[13];
    const float* rel_pri   = (const float*)d_in[14];
    const float* rel_att   = (const float*)d_in[15];
    const float* rel_msg   = (const float*)d_in[16];
    const float* skip      = (const float*)d_in[17];
    const float* ln_g      = (const float*)d_in[18];
    const float* ln_b      = (const float*)d_in[19];
    float* out = (float*)d_out;

    char* p = (char*)d_ws;
    auto alloc = [&](size_t bytes) -> void* {
        void* q = (void*)p;
        p += (bytes + 255) & ~(size_t)255;
        return q;
    };
    float* h0   = (float*)alloc((size_t)N_NODES*HID*4);
    float* Qb   = (float*)alloc((size_t)N_NODES*HID*4);
    float* KVpf = (float*)alloc((size_t)N_NODES*256*4);   // packed K/V interleaved
    float* aggb = (float*)alloc((size_t)N_NODES*HID*4);
    float* rmT  = (float*)alloc((size_t)2*RR*HH*DKK*DKK*4);
    int* ib     = (int*)alloc((size_t)(2*N_NODES + 8)*4);
    int* deg  = ib;
    int* tmpN = ib + N_NODES;
    int* cntT = ib + 2*N_NODES;
    int* tmpT = ib + 2*N_NODES + 4;
    int* off   = (int*)alloc((size_t)(N_NODES+1)*4);
    int* offT  = (int*)alloc(16);
    int* epk   = (int*)alloc((size_t)E_EDGES*4);
    int* nperm = (int*)alloc((size_t)N_NODES*4);

    const int* esrc = edge_index;
    const int* edst = edge_index + E_EDGES;

    hipMemsetAsync(ib, 0, (size_t)(2*N_NODES + 8)*4, stream);
    k_hist_nodes<<<(N_NODES+255)/256, 256, 0, stream>>>(node_types, cntT, N_NODES);
    k_hist_edges<<<(E_EDGES+255)/256, 256, 0, stream>>>(edst, deg, E_EDGES);
    k_offT<<<1, 1, 0, stream>>>(cntT, offT);
    k_scan<<<1, 1024, 0, stream>>>(deg, off, N_NODES);
    k_scatter_nodes<<<(N_NODES+255)/256, 256, 0, stream>>>(node_types, offT, tmpT, nperm, N_NODES);
    k_scatter_edges<<<(E_EDGES+255)/256, 256, 0, stream>>>(esrc, edst, edge_types, off, tmpN, epk, E_EDGES);
    k_transpose_rmsg<<<(2*RR*HH*DKK*DKK+255)/256, 256, 0, stream>>>(rel_msg, rmT);

    dim3 gg((N_NODES+63)/64, TT);
    k_adapt<<<gg, 256, 0, stream>>>(x, W_adapt, b_adapt, nperm, offT, cntT, h0);

    for (int l = 0; l < 2; ++l){
        const float* hin = (l == 0) ? h0 : out;
        const size_t WOFF = (size_t)l*TT*HID*HID;
        const size_t BOFF = (size_t)l*TT*HID;
        k_kqv<<<gg, 256, 0, stream>>>(hin, Wk+WOFF, bk+BOFF, Wq+WOFF, bq+BOFF, Wv+WOFF, bv+BOFF,
                                      nperm, offT, cntT, Qb, (float2*)KVpf);
        k_attn<<<(N_NODES+7)/8, 256, 0, stream>>>(Qb, (const float4*)KVpf,
            rel_att + (size_t)l*RR*HH*DKK*DKK,
            rmT + (size_t)l*RR*HH*DKK*DKK,
            rel_pri + (size_t)l*RR*HH,
            off, epk, aggb);
        if (l == 0)
            k_out<true><<<gg, 256, 0, stream>>>(aggb, Wa+WOFF, ba+BOFF, hin, skip + l*TT,
                                                ln_g, ln_b, nperm, offT, cntT, out);
        else
            k_out<false><<<gg, 256, 0, stream>>>(aggb, Wa+WOFF, ba+BOFF, hin, skip + l*TT,
                                                 ln_g, ln_b, nperm, offT, cntT, out);
    }
}

// Round 4
// 1707.537 us; speedup vs baseline: 1.5170x; 1.0693x over previous
//
#include <hip/hip_runtime.h>
#include <math.h>

#define N_NODES 50000
#define E_EDGES 400000
#define IN_DIM  256
#define HID     128
#define TT      3
#define RR      4
#define HH      8
#define DKK     16

typedef __attribute__((ext_vector_type(8))) short bf16x8;
typedef __attribute__((ext_vector_type(4))) float f32x4;

__device__ __forceinline__ float geluf(float v){
    return 0.5f * v * (1.f + erff(v * 0.70710678118654752440f));
}

__device__ __forceinline__ unsigned short f2bf(float f){
    union { float f; unsigned u; } v; v.f = f;
    unsigned r = v.u + 0x7FFF + ((v.u >> 16) & 1);   // round-to-nearest-even
    return (unsigned short)(r >> 16);
}

__device__ __forceinline__ bf16x8 cvt8(float4 a, float4 b){
    bf16x8 v;
    v[0]=(short)f2bf(a.x); v[1]=(short)f2bf(a.y); v[2]=(short)f2bf(a.z); v[3]=(short)f2bf(a.w);
    v[4]=(short)f2bf(b.x); v[5]=(short)f2bf(b.y); v[6]=(short)f2bf(b.z); v[7]=(short)f2bf(b.w);
    return v;
}

// ---------------- setup kernels ----------------

__global__ void k_hist_nodes(const int* __restrict__ nt, int* __restrict__ cntT, int n){
    int i = blockIdx.x*blockDim.x + threadIdx.x;
    if (i < n) atomicAdd(&cntT[nt[i]], 1);
}

__global__ void k_offT(const int* __restrict__ cntT, int* __restrict__ offT){
    if (threadIdx.x == 0 && blockIdx.x == 0){
        int a = 0;
        for (int t = 0; t < TT; ++t){ offT[t] = a; a += cntT[t]; }
        offT[TT] = a;
    }
}

__global__ void k_scatter_nodes(const int* __restrict__ nt, const int* __restrict__ offT,
                                int* __restrict__ tmpT, int* __restrict__ nperm,
                                int* __restrict__ inv, int n){
    int i = blockIdx.x*blockDim.x + threadIdx.x;
    if (i < n){
        int t = nt[i];
        int p = offT[t] + atomicAdd(&tmpT[t], 1);
        nperm[p] = i;
        inv[i] = p;
    }
}

// degree histogram over PERMUTED dst ids
__global__ void k_hist_edges(const int* __restrict__ edst, const int* __restrict__ inv,
                             int* __restrict__ deg, int e){
    int i = blockIdx.x*blockDim.x + threadIdx.x;
    if (i < e) atomicAdd(&deg[inv[edst[i]]], 1);
}

__global__ void k_scan(const int* __restrict__ deg, int* __restrict__ off, int n){
    __shared__ int sums[1024];
    int tid = threadIdx.x;
    int chunk = (n + 1023) >> 10;
    int st = tid*chunk, en = st + chunk; if (en > n) en = n;
    int s = 0;
    for (int i = st; i < en; ++i) s += deg[i];
    sums[tid] = s;
    __syncthreads();
    for (int o = 1; o < 1024; o <<= 1){
        int v = (tid >= o) ? sums[tid-o] : 0;
        __syncthreads();
        sums[tid] += v;
        __syncthreads();
    }
    int run = (tid == 0) ? 0 : sums[tid-1];
    for (int i = st; i < en; ++i){ off[i] = run; run += deg[i]; }
    if (tid == 1023) off[n] = run;
}

// sorted packed edges in permuted space: epk[p] = psrc | (type<<16)
__global__ void k_scatter_edges(const int* __restrict__ esrc, const int* __restrict__ edst,
                                const int* __restrict__ ety, const int* __restrict__ inv,
                                const int* __restrict__ off, int* __restrict__ tmpN,
                                int* __restrict__ epk, int e){
    int i = blockIdx.x*blockDim.x + threadIdx.x;
    if (i < e){
        int d = inv[edst[i]];
        int p = off[d] + atomicAdd(&tmpN[d], 1);
        epk[p] = inv[esrc[i]] | (ety[i] << 16);
    }
}

// rel_msg [2][R][H][d][f] -> rmT [2][R][H][f][d]
__global__ void k_transpose_rmsg(const float* __restrict__ rm, float* __restrict__ rmT){
    int i = blockIdx.x*blockDim.x + threadIdx.x;
    const int tot = 2*RR*HH*DKK*DKK;
    if (i < tot){
        int f = i & 15;
        int d = (i >> 4) & 15;
        int rest = i >> 8;
        rmT[(rest*DKK + f)*DKK + d] = rm[i];
    }
}

// convert fp32 weights [mat][K][N] -> bf16 transposed [mat][N][K]
__global__ void k_cvt_w(const float* __restrict__ src, short* __restrict__ dst,
                        int K, int N, int total){
    int i = blockIdx.x*256 + threadIdx.x;
    if (i >= total) return;
    int mat = i / (K*N);
    int rem = i - mat*K*N;
    int k = rem / N, c = rem - k*N;
    dst[(size_t)mat*K*N + (size_t)c*K + k] = (short)f2bf(src[i]);
}

// ---------------- MFMA GEMM building blocks ----------------
// block: 64 rows x 128 cols, 256 thr / 4 waves; wave tile 64x32 (4m x 2n).
// LDS: Asw[64][128] bf16 swizzled, Bsw[128][128] bf16 swizzled (slot ^= row&7).
// frag layout (16x16x32): A lane l -> row l&15, k = (l>>4)*8+j ; B same with col;
// D lane l -> col l&15, row (l>>4)*4+i.

#define STAGE_B(WT, KTOT, KC) \
  for (int i_ = tid; i_ < 128*16; i_ += 256){ \
    int colb = i_ >> 4, slot = i_ & 15; \
    bf16x8 v_ = *(const bf16x8*)&(WT)[(size_t)colb*(KTOT) + (KC) + slot*8]; \
    *(bf16x8*)&Bsw[(colb*16 + (slot ^ (colb&7)))*8] = v_; \
  }

#define MFMA_CORE(ACC) \
  _Pragma("unroll") \
  for (int kk8 = 0; kk8 < 16; kk8 += 4){ \
    int ks = kk8 + kq; \
    bf16x8 afr[4]; bf16x8 bfr[2]; \
    _Pragma("unroll") for (int m_=0;m_<4;++m_) \
      afr[m_] = *(bf16x8*)&Asw[((m_*16+wl)*16 + (ks ^ wl7))*8]; \
    _Pragma("unroll") for (int n_=0;n_<2;++n_) \
      bfr[n_] = *(bf16x8*)&Bsw[((wv*32+n_*16+wl)*16 + (ks ^ wl7))*8]; \
    _Pragma("unroll") for (int m_=0;m_<4;++m_) \
      _Pragma("unroll") for (int n_=0;n_<2;++n_) \
        ACC[m_][n_] = __builtin_amdgcn_mfma_f32_16x16x32_bf16(afr[m_], bfr[n_], ACC[m_][n_], 0, 0, 0); \
  }

#define ZERO_ACC(ACC) \
  _Pragma("unroll") for (int m_=0;m_<4;++m_) \
    _Pragma("unroll") for (int n_=0;n_<2;++n_) \
      ACC[m_][n_] = (f32x4){0.f,0.f,0.f,0.f};

// ---------------- adapt: h0p = tanh(x[nperm] @ W_adapt[t] + b), K=256 ----------------

__global__ __launch_bounds__(256) void k_adapt(
    const float* __restrict__ x, const short* __restrict__ Wta, const float* __restrict__ b_,
    const int* __restrict__ nperm, const int* __restrict__ offT, const int* __restrict__ cntT,
    float* __restrict__ hp)
{
    const int t = blockIdx.y;
    const int cnt = cntT[t];
    const int base = blockIdx.x * 64;
    if (base >= cnt) return;
    const int gbase = offT[t] + base;
    __shared__ short Asw[64*128];
    __shared__ short Bsw[128*128];
    __shared__ int nid[64];
    const int tid = threadIdx.x;
    if (tid < 64){
        int ii = base + tid;
        nid[tid] = (ii < cnt) ? nperm[offT[t] + ii] : -1;
    }
    __syncthreads();
    const int lane = tid & 63, wv = tid >> 6;
    const int wl = lane & 15, kq = lane >> 4, wl7 = wl & 7;
    const short* Wt = Wta + (size_t)t*HID*IN_DIM;

    f32x4 acc[4][2];
    ZERO_ACC(acc)
    for (int kc = 0; kc < IN_DIM; kc += 128){
        for (int i_ = tid; i_ < 64*16; i_ += 256){
            int rowa = i_ >> 4, slot = i_ & 15;
            int node = nid[rowa];
            bf16x8 v_ = {0,0,0,0,0,0,0,0};
            if (node >= 0){
                const float* sp = x + (size_t)node*IN_DIM + kc + slot*8;
                v_ = cvt8(*(const float4*)sp, *(const float4*)(sp+4));
            }
            *(bf16x8*)&Asw[(rowa*16 + (slot ^ (rowa&7)))*8] = v_;
        }
        STAGE_B(Wt, IN_DIM, kc)
        __syncthreads();
        MFMA_CORE(acc)
        __syncthreads();
    }
#pragma unroll
    for (int n = 0; n < 2; ++n){
        int col = wv*32 + n*16 + wl;
        float bb = b_[t*HID + col];
#pragma unroll
        for (int m = 0; m < 4; ++m){
#pragma unroll
            for (int i = 0; i < 4; ++i){
                int row = m*16 + kq*4 + i;
                if (base + row < cnt)
                    hp[(size_t)(gbase+row)*HID + col] = tanhf(acc[m][n][i] + bb);
            }
        }
    }
}

// ---------------- merged K/Q/V MFMA GEMM ----------------
// A (hp rows, permuted, linear) staged once; 3 weight passes.
// K/V written packed: KVpf[node*256 + (h*8+jj)*4 + {0,1:K | 2,3:V}]

__global__ __launch_bounds__(256) void k_kqv(
    const float* __restrict__ hp,
    const short* __restrict__ Wtk, const float* __restrict__ bk_,
    const short* __restrict__ Wtq, const float* __restrict__ bq_,
    const short* __restrict__ Wtv, const float* __restrict__ bv_,
    const int* __restrict__ offT, const int* __restrict__ cntT,
    float* __restrict__ Qp, float* __restrict__ KVpf)
{
    const int t = blockIdx.y;
    const int cnt = cntT[t];
    const int base = blockIdx.x * 64;
    if (base >= cnt) return;
    const int gbase = offT[t] + base;
    __shared__ short Asw[64*128];
    __shared__ short Bsw[128*128];
    const int tid = threadIdx.x;
    const int lane = tid & 63, wv = tid >> 6;
    const int wl = lane & 15, kq = lane >> 4, wl7 = wl & 7;

    // stage A once (linear, coalesced, fp32->bf16)
    for (int i_ = tid; i_ < 64*16; i_ += 256){
        int rowa = i_ >> 4, slot = i_ & 15;
        const float* sp = hp + (size_t)(gbase + rowa)*HID + slot*8;
        *(bf16x8*)&Asw[(rowa*16 + (slot ^ (rowa&7)))*8] = cvt8(*(const float4*)sp, *(const float4*)(sp+4));
    }

    // ---- pass K ----
    {
        const short* Wt = Wtk + (size_t)t*HID*HID;
        STAGE_B(Wt, HID, 0)
        __syncthreads();
        f32x4 acc[4][2]; ZERO_ACC(acc)
        MFMA_CORE(acc)
        __syncthreads();
#pragma unroll
        for (int n = 0; n < 2; ++n){
            int col = wv*32 + n*16 + wl;
            float bb = bk_[t*HID + col];
            int lane4 = ((col>>4)*8 + ((col&15)>>1))*4 + (col&1);
#pragma unroll
            for (int m = 0; m < 4; ++m){
#pragma unroll
                for (int i = 0; i < 4; ++i){
                    int row = m*16 + kq*4 + i;
                    if (base + row < cnt)
                        KVpf[(size_t)(gbase+row)*256 + lane4] = acc[m][n][i] + bb;
                }
            }
        }
    }
    // ---- pass Q ----
    {
        const short* Wt = Wtq + (size_t)t*HID*HID;
        STAGE_B(Wt, HID, 0)
        __syncthreads();
        f32x4 acc[4][2]; ZERO_ACC(acc)
        MFMA_CORE(acc)
        __syncthreads();
#pragma unroll
        for (int n = 0; n < 2; ++n){
            int col = wv*32 + n*16 + wl;
            float bb = bq_[t*HID + col];
#pragma unroll
            for (int m = 0; m < 4; ++m){
#pragma unroll
                for (int i = 0; i < 4; ++i){
                    int row = m*16 + kq*4 + i;
                    if (base + row < cnt)
                        Qp[(size_t)(gbase+row)*HID + col] = acc[m][n][i] + bb;
                }
            }
        }
    }
    // ---- pass V ----
    {
        const short* Wt = Wtv + (size_t)t*HID*HID;
        STAGE_B(Wt, HID, 0)
        __syncthreads();
        f32x4 acc[4][2]; ZERO_ACC(acc)
        MFMA_CORE(acc)
        __syncthreads();
#pragma unroll
        for (int n = 0; n < 2; ++n){
            int col = wv*32 + n*16 + wl;
            float bb = bv_[t*HID + col];
            int lane4 = ((col>>4)*8 + ((col&15)>>1))*4 + (col&1) + 2;
#pragma unroll
            for (int m = 0; m < 4; ++m){
#pragma unroll
                for (int i = 0; i < 4; ++i){
                    int row = m*16 + kq*4 + i;
                    if (base + row < cnt)
                        KVpf[(size_t)(gbase+row)*256 + lane4] = acc[m][n][i] + bb;
                }
            }
        }
    }
}

// ---------------- per-node attention (permuted space, unchanged math) ----------------

#define LOADKV4(S, P) \
    int pk##S##0 = epk[(P)+0], pk##S##1 = epk[(P)+1], pk##S##2 = epk[(P)+2], pk##S##3 = epk[(P)+3]; \
    float4 kv##S##0 = KVp[(size_t)(pk##S##0 & 0xFFFF)*64 + lane]; \
    float4 kv##S##1 = KVp[(size_t)(pk##S##1 & 0xFFFF)*64 + lane]; \
    float4 kv##S##2 = KVp[(size_t)(pk##S##2 & 0xFFFF)*64 + lane]; \
    float4 kv##S##3 = KVp[(size_t)(pk##S##3 & 0xFFFF)*64 + lane];

#define LOGIT_I(S, i) \
    float part##S##i; { \
        int r_ = pk##S##i >> 16; \
        float qa_ = (r_==0)?qa0##S:(r_==1)?qa1##S:(r_==2)?qa2##S:qa3##S; \
        float qb_ = (r_==0)?qb0##S:(r_==1)?qb1##S:(r_==2)?qb2##S:qb3##S; \
        part##S##i = fmaf(kv##S##i.x, qa_, kv##S##i.y * qb_); \
    } \
    part##S##i += __shfl_xor(part##S##i, 1); \
    part##S##i += __shfl_xor(part##S##i, 2); \
    part##S##i += __shfl_xor(part##S##i, 4);

#define ACC_I(S, i) { \
    int r_ = pk##S##i >> 16; \
    float e_ = __expf(part##S##i - mn##S); \
    l##S += e_; \
    float w0_=(r_==0)?e_:0.f, w1_=(r_==1)?e_:0.f, w2_=(r_==2)?e_:0.f, w3_=(r_==3)?e_:0.f; \
    cx0##S = fmaf(w0_, kv##S##i.z, cx0##S); cy0##S = fmaf(w0_, kv##S##i.w, cy0##S); \
    cx1##S = fmaf(w1_, kv##S##i.z, cx1##S); cy1##S = fmaf(w1_, kv##S##i.w, cy1##S); \
    cx2##S = fmaf(w2_, kv##S##i.z, cx2##S); cy2##S = fmaf(w2_, kv##S##i.w, cy2##S); \
    cx3##S = fmaf(w3_, kv##S##i.z, cx3##S); cy3##S = fmaf(w3_, kv##S##i.w, cy3##S); }

#define BATCH4(S) \
    LOGIT_I(S,0) LOGIT_I(S,1) LOGIT_I(S,2) LOGIT_I(S,3) \
    float bm##S = fmaxf(fmaxf(part##S##0, part##S##1), fmaxf(part##S##2, part##S##3)); \
    float mn##S = fmaxf(m##S, bm##S); \
    float sc##S = __expf(m##S - mn##S); \
    m##S = mn##S; l##S *= sc##S; \
    cx0##S *= sc##S; cx1##S *= sc##S; cx2##S *= sc##S; cx3##S *= sc##S; \
    cy0##S *= sc##S; cy1##S *= sc##S; cy2##S *= sc##S; cy3##S *= sc##S; \
    ACC_I(S,0) ACC_I(S,1) ACC_I(S,2) ACC_I(S,3)

#define TAIL4(S, P, P1) { \
    int pk##S##0 = epk[P]; \
    int pk##S##1 = epk[((P)+1 < (P1)) ? (P)+1 : (P1)-1]; \
    int pk##S##2 = epk[((P)+2 < (P1)) ? (P)+2 : (P1)-1]; \
    int pk##S##3 = epk[((P)+3 < (P1)) ? (P)+3 : (P1)-1]; \
    float4 kv##S##0 = KVp[(size_t)(pk##S##0 & 0xFFFF)*64 + lane]; \
    float4 kv##S##1 = KVp[(size_t)(pk##S##1 & 0xFFFF)*64 + lane]; \
    float4 kv##S##2 = KVp[(size_t)(pk##S##2 & 0xFFFF)*64 + lane]; \
    float4 kv##S##3 = KVp[(size_t)(pk##S##3 & 0xFFFF)*64 + lane]; \
    LOGIT_I(S,0) LOGIT_I(S,1) LOGIT_I(S,2) LOGIT_I(S,3) \
    if ((P)+1 >= (P1)) part##S##1 = -INFINITY; \
    if ((P)+2 >= (P1)) part##S##2 = -INFINITY; \
    if ((P)+3 >= (P1)) part##S##3 = -INFINITY; \
    float bm##S = fmaxf(fmaxf(part##S##0, part##S##1), fmaxf(part##S##2, part##S##3)); \
    float mn##S = fmaxf(m##S, bm##S); \
    float sc##S = __expf(m##S - mn##S); \
    m##S = mn##S; l##S *= sc##S; \
    cx0##S *= sc##S; cx1##S *= sc##S; cx2##S *= sc##S; cx3##S *= sc##S; \
    cy0##S *= sc##S; cy1##S *= sc##S; cy2##S *= sc##S; cy3##S *= sc##S; \
    ACC_I(S,0) ACC_I(S,1) ACC_I(S,2) ACC_I(S,3) }

#define FINAL2(RIDX) { \
    const float* rm = rmT + (((size_t)((RIDX)*HH + h))*DKK + d0)*DKK; \
    float4 A0 = *(const float4*)(rm + 0),  A1 = *(const float4*)(rm + 4); \
    float4 A2 = *(const float4*)(rm + 8),  A3 = *(const float4*)(rm + 12); \
    float4 B0 = *(const float4*)(rm + 16), B1 = *(const float4*)(rm + 20); \
    float4 B2 = *(const float4*)(rm + 24), B3 = *(const float4*)(rm + 28); \
    float yA[16], yB[16]; \
    _Pragma("unroll") \
    for (int u = 0; u < 8; ++u){ \
        yA[2*u]   = __shfl(cx##RIDX##A, (h<<3) + u); \
        yA[2*u+1] = __shfl(cy##RIDX##A, (h<<3) + u); \
        yB[2*u]   = __shfl(cx##RIDX##B, (h<<3) + u); \
        yB[2*u+1] = __shfl(cy##RIDX##B, (h<<3) + u); \
    } \
    o0A += yA[0]*A0.x + yA[1]*A0.y + yA[2]*A0.z + yA[3]*A0.w \
         + yA[4]*A1.x + yA[5]*A1.y + yA[6]*A1.z + yA[7]*A1.w \
         + yA[8]*A2.x + yA[9]*A2.y + yA[10]*A2.z + yA[11]*A2.w \
         + yA[12]*A3.x + yA[13]*A3.y + yA[14]*A3.z + yA[15]*A3.w; \
    o1A += yA[0]*B0.x + yA[1]*B0.y + yA[2]*B0.z + yA[3]*B0.w \
         + yA[4]*B1.x + yA[5]*B1.y + yA[6]*B1.z + yA[7]*B1.w \
         + yA[8]*B2.x + yA[9]*B2.y + yA[10]*B2.z + yA[11]*B2.w \
         + yA[12]*B3.x + yA[13]*B3.y + yA[14]*B3.z + yA[15]*B3.w; \
    o0B += yB[0]*A0.x + yB[1]*A0.y + yB[2]*A0.z + yB[3]*A0.w \
         + yB[4]*A1.x + yB[5]*A1.y + yB[6]*A1.z + yB[7]*A1.w \
         + yB[8]*A2.x + yB[9]*A2.y + yB[10]*A2.z + yB[11]*A2.w \
         + yB[12]*A3.x + yB[13]*A3.y + yB[14]*A3.z + yB[15]*A3.w; \
    o1B += yB[0]*B0.x + yB[1]*B0.y + yB[2]*B0.z + yB[3]*B0.w \
         + yB[4]*B1.x + yB[5]*B1.y + yB[6]*B1.z + yB[7]*B1.w \
         + yB[8]*B2.x + yB[9]*B2.y + yB[10]*B2.z + yB[11]*B2.w \
         + yB[12]*B3.x + yB[13]*B3.y + yB[14]*B3.z + yB[15]*B3.w; }

__global__ __launch_bounds__(256) void k_attn(
    const float* __restrict__ Qp, const float4* __restrict__ KVp,
    const float* __restrict__ Ratt, const float* __restrict__ rmT,
    const float* __restrict__ pri,
    const int* __restrict__ off, const int* __restrict__ epk,
    float* __restrict__ agg)
{
    const int wid = threadIdx.x >> 6;
    const int n0 = blockIdx.x*8 + wid*2;
    if (n0 >= N_NODES) return;
    const bool hasB = (n0 + 1) < N_NODES;
    const int lane = threadIdx.x & 63;
    const int h  = lane >> 3;
    const int d0 = (lane & 7) * 2;

    const float* qpA = Qp + (size_t)n0*HID + h*DKK;
    const float* qpB = Qp + (size_t)(hasB ? n0+1 : n0)*HID + h*DKK;
    float qvA[16], qvB[16];
#pragma unroll
    for (int u = 0; u < 4; ++u){
        float4 ta = *(const float4*)(qpA + 4*u);
        float4 tb = *(const float4*)(qpB + 4*u);
        qvA[4*u+0]=ta.x; qvA[4*u+1]=ta.y; qvA[4*u+2]=ta.z; qvA[4*u+3]=ta.w;
        qvB[4*u+0]=tb.x; qvB[4*u+1]=tb.y; qvB[4*u+2]=tb.z; qvB[4*u+3]=tb.w;
    }

    float qa0A,qa1A,qa2A,qa3A,qb0A,qb1A,qb2A,qb3A;
    float qa0B,qa1B,qa2B,qa3B,qb0B,qb1B,qb2B,qb3B;
#pragma unroll
    for (int r = 0; r < RR; ++r){
        const float* ar = Ratt + (((size_t)(r*HH + h))*DKK + d0)*DKK;
        float s0A=0.f, s1A=0.f, s0B=0.f, s1B=0.f;
#pragma unroll
        for (int u = 0; u < 4; ++u){
            float4 a0 = *(const float4*)(ar + 4*u);
            float4 a1 = *(const float4*)(ar + DKK + 4*u);
            s0A += a0.x*qvA[4*u+0] + a0.y*qvA[4*u+1] + a0.z*qvA[4*u+2] + a0.w*qvA[4*u+3];
            s1A += a1.x*qvA[4*u+0] + a1.y*qvA[4*u+1] + a1.z*qvA[4*u+2] + a1.w*qvA[4*u+3];
            s0B += a0.x*qvB[4*u+0] + a0.y*qvB[4*u+1] + a0.z*qvB[4*u+2] + a0.w*qvB[4*u+3];
            s1B += a1.x*qvB[4*u+0] + a1.y*qvB[4*u+1] + a1.z*qvB[4*u+2] + a1.w*qvB[4*u+3];
        }
        float pr = pri[r*HH + h] * 0.25f;
        s0A *= pr; s1A *= pr; s0B *= pr; s1B *= pr;
        if      (r == 0){ qa0A=s0A; qb0A=s1A; qa0B=s0B; qb0B=s1B; }
        else if (r == 1){ qa1A=s0A; qb1A=s1A; qa1B=s0B; qb1B=s1B; }
        else if (r == 2){ qa2A=s0A; qb2A=s1A; qa2B=s0B; qb2B=s1B; }
        else            { qa3A=s0A; qb3A=s1A; qa3B=s0B; qb3B=s1B; }
    }

    float mA=-INFINITY, lA=0.f, cx0A=0.f,cx1A=0.f,cx2A=0.f,cx3A=0.f, cy0A=0.f,cy1A=0.f,cy2A=0.f,cy3A=0.f;
    float mB=-INFINITY, lB=0.f, cx0B=0.f,cx1B=0.f,cx2B=0.f,cx3B=0.f, cy0B=0.f,cy1B=0.f,cy2B=0.f,cy3B=0.f;

    int pa = off[n0],  ea = off[n0+1];
    int pb = 0, eb = 0;
    if (hasB){ pb = ea; eb = off[n0+2]; }

    while (pa + 4 <= ea && pb + 4 <= eb){
        LOADKV4(A, pa)
        LOADKV4(B, pb)
        BATCH4(A)
        BATCH4(B)
        pa += 4; pb += 4;
    }
    while (pa + 4 <= ea){
        LOADKV4(A, pa)
        BATCH4(A)
        pa += 4;
    }
    while (pb + 4 <= eb){
        LOADKV4(B, pb)
        BATCH4(B)
        pb += 4;
    }
    if (pa < ea) TAIL4(A, pa, ea)
    if (pb < eb) TAIL4(B, pb, eb)

    float o0A=0.f, o1A=0.f, o0B=0.f, o1B=0.f;
    FINAL2(0)
    FINAL2(1)
    FINAL2(2)
    FINAL2(3)

    const float invA = 1.f / fmaxf(lA, 1e-9f);
    *(float2*)(agg + (size_t)n0*HID + h*DKK + d0) = make_float2(o0A*invA, o1A*invA);
    if (hasB){
        const float invB = 1.f / fmaxf(lB, 1e-9f);
        *(float2*)(agg + (size_t)(n0+1)*HID + h*DKK + d0) = make_float2(o0B*invB, o1B*invB);
    }
}

// ---------------- output MFMA GEMM: gelu(aggp) @ Wa + blend (+LN+ReLU) ----------------
// USE_LN=true: writes hp (permuted, in-place with hin allowed).
// USE_LN=false: scatter-writes `out` in ORIGINAL node order via nperm.

template<bool USE_LN>
__global__ __launch_bounds__(256) void k_out(
    const float* __restrict__ aggp, const short* __restrict__ Wta, const float* __restrict__ ba_,
    const float* __restrict__ hin, const float* __restrict__ skipl,
    const float* __restrict__ gam, const float* __restrict__ bet,
    const int* __restrict__ nperm, const int* __restrict__ offT, const int* __restrict__ cntT,
    float* __restrict__ hout)
{
    const int t = blockIdx.y;
    const int cnt = cntT[t];
    const int base = blockIdx.x * 64;
    if (base >= cnt) return;
    const int gbase = offT[t] + base;
    __shared__ short Asw[64*128];
    __shared__ short Bsw[128*128];
    __shared__ int nid[64];
    const int tid = threadIdx.x;
    if (!USE_LN && tid < 64){
        int ii = base + tid;
        nid[tid] = (ii < cnt) ? nperm[offT[t] + ii] : -1;
    }
    const int lane = tid & 63, wv = tid >> 6;
    const int wl = lane & 15, kq = lane >> 4, wl7 = wl & 7;

    // stage A = gelu(aggp rows), linear
    for (int i_ = tid; i_ < 64*16; i_ += 256){
        int rowa = i_ >> 4, slot = i_ & 15;
        const float* sp = aggp + (size_t)(gbase + rowa)*HID + slot*8;
        float4 f0 = *(const float4*)sp, f1 = *(const float4*)(sp+4);
        f0.x=geluf(f0.x); f0.y=geluf(f0.y); f0.z=geluf(f0.z); f0.w=geluf(f0.w);
        f1.x=geluf(f1.x); f1.y=geluf(f1.y); f1.z=geluf(f1.z); f1.w=geluf(f1.w);
        *(bf16x8*)&Asw[(rowa*16 + (slot ^ (rowa&7)))*8] = cvt8(f0, f1);
    }
    {
        const short* Wt = Wta + (size_t)t*HID*HID;
        STAGE_B(Wt, HID, 0)
    }
    __syncthreads();
    f32x4 acc[4][2]; ZERO_ACC(acc)
    MFMA_CORE(acc)
    __syncthreads();

    // spill D to LDS (alias Bsw as 64x128 f32)
    float* smemf = (float*)Bsw;
#pragma unroll
    for (int n = 0; n < 2; ++n){
        int col = wv*32 + n*16 + wl;
#pragma unroll
        for (int m = 0; m < 4; ++m){
#pragma unroll
            for (int i = 0; i < 4; ++i){
                int row = m*16 + kq*4 + i;
                smemf[row*128 + col] = acc[m][n][i];
            }
        }
    }
    __syncthreads();

    // per-row: bias + blend (+LN+ReLU) ; 4 threads per row
    const float alpha = 1.f / (1.f + __expf(-skipl[t]));
    const float onem = 1.f - alpha;
    const int row = tid >> 2;
    const int part = tid & 3;
    const int cbase = part * 32;
    float vals[32];
    float s = 0.f, s2 = 0.f;
#pragma unroll
    for (int u = 0; u < 8; ++u){
        float4 d  = *(float4*)&smemf[row*128 + cbase + u*4];
        float4 bb = *(const float4*)&ba_[t*HID + cbase + u*4];
        float4 hv = *(const float4*)&hin[(size_t)(gbase+row)*HID + cbase + u*4];
        float v0 = (d.x + bb.x)*alpha + hv.x*onem;
        float v1 = (d.y + bb.y)*alpha + hv.y*onem;
        float v2 = (d.z + bb.z)*alpha + hv.z*onem;
        float v3 = (d.w + bb.w)*alpha + hv.w*onem;
        vals[u*4+0]=v0; vals[u*4+1]=v1; vals[u*4+2]=v2; vals[u*4+3]=v3;
        s += v0+v1+v2+v3;
        s2 += v0*v0+v1*v1+v2*v2+v3*v3;
    }
    if (USE_LN){
        s  += __shfl_xor(s, 1);  s  += __shfl_xor(s, 2);
        s2 += __shfl_xor(s2, 1); s2 += __shfl_xor(s2, 2);
        float mu = s * (1.f/128.f);
        float var = s2 * (1.f/128.f) - mu*mu;
        float rstd = rsqrtf(var + 1e-5f);
        if (base + row < cnt){
#pragma unroll
            for (int u = 0; u < 8; ++u){
                float4 g4 = *(const float4*)&gam[t*HID + cbase + u*4];
                float4 e4 = *(const float4*)&bet[t*HID + cbase + u*4];
                float4 r4;
                r4.x = fmaxf((vals[u*4+0]-mu)*rstd*g4.x + e4.x, 0.f);
                r4.y = fmaxf((vals[u*4+1]-mu)*rstd*g4.y + e4.y, 0.f);
                r4.z = fmaxf((vals[u*4+2]-mu)*rstd*g4.z + e4.z, 0.f);
                r4.w = fmaxf((vals[u*4+3]-mu)*rstd*g4.w + e4.w, 0.f);
                *(float4*)&hout[(size_t)(gbase+row)*HID + cbase + u*4] = r4;
            }
        }
    } else {
        int node = nid[row];
        if (node >= 0){
#pragma unroll
            for (int u = 0; u < 8; ++u){
                float4 r4 = make_float4(vals[u*4+0], vals[u*4+1], vals[u*4+2], vals[u*4+3]);
                *(float4*)&hout[(size_t)node*HID + cbase + u*4] = r4;
            }
        }
    }
}

// ---------------- launch ----------------

extern "C" void kernel_launch(void* const* d_in, const int* in_sizes, int n_in,
                              void* d_out, int out_size, void* d_ws, size_t ws_size,
                              hipStream_t stream)
{
    const float* x         = (const float*)d_in[0];
    const int*   node_types= (const int*)  d_in[1];
    const int*   edge_index= (const int*)  d_in[2];
    const int*   edge_types= (const int*)  d_in[3];
    const float* W_adapt   = (const float*)d_in[4];
    const float* b_adapt   = (const float*)d_in[5];
    const float* Wk        = (const float*)d_in[6];
    const float* bk        = (const float*)d_in[7];
    const float* Wq        = (const float*)d_in[8];
    const float* bq        = (const float*)d_in[9];
    const float* Wv        = (const float*)d_in[10];
    const float* bv        = (const float*)d_in[11];
    const float* Wa        = (const float*)d_in[12];
    const float* ba        = (const float*)d_in[13];
    const float* rel_pri   = (const float*)d_in[14];
    const float* rel_att   = (const float*)d_in[15];
    const float* rel_msg   = (const float*)d_in[16];
    const float* skip      = (const float*)d_in[17];
    const float* ln_g      = (const float*)d_in[18];
    const float* ln_b      = (const float*)d_in[19];
    float* out = (float*)d_out;

    char* p = (char*)d_ws;
    auto alloc = [&](size_t bytes) -> void* {
        void* q = (void*)p;
        p += (bytes + 255) & ~(size_t)255;
        return q;
    };
    float* hp    = (float*)alloc((size_t)N_NODES*HID*4);
    float* Qp    = (float*)alloc((size_t)N_NODES*HID*4);
    float* KVpf  = (float*)alloc((size_t)N_NODES*256*4);
    float* aggp  = (float*)alloc((size_t)N_NODES*HID*4);
    float* rmT   = (float*)alloc((size_t)2*RR*HH*DKK*DKK*4);
    short* Wta   = (short*)alloc((size_t)TT*IN_DIM*HID*2);
    short* Wtk   = (short*)alloc((size_t)2*TT*HID*HID*2);
    short* Wtq   = (short*)alloc((size_t)2*TT*HID*HID*2);
    short* Wtv   = (short*)alloc((size_t)2*TT*HID*HID*2);
    short* Wtao  = (short*)alloc((size_t)2*TT*HID*HID*2);
    int* ib      = (int*)alloc((size_t)(2*N_NODES + 8)*4);
    int* deg  = ib;
    int* tmpN = ib + N_NODES;
    int* cntT = ib + 2*N_NODES;
    int* tmpT = ib + 2*N_NODES + 4;
    int* off   = (int*)alloc((size_t)(N_NODES+1)*4);
    int* offT  = (int*)alloc(16);
    int* epk   = (int*)alloc((size_t)E_EDGES*4);
    int* nperm = (int*)alloc((size_t)N_NODES*4);
    int* inv   = (int*)alloc((size_t)N_NODES*4);

    const int* esrc = edge_index;
    const int* edst = edge_index + E_EDGES;

    hipMemsetAsync(ib, 0, (size_t)(2*N_NODES + 8)*4, stream);
    k_hist_nodes<<<(N_NODES+255)/256, 256, 0, stream>>>(node_types, cntT, N_NODES);
    k_offT<<<1, 1, 0, stream>>>(cntT, offT);
    k_scatter_nodes<<<(N_NODES+255)/256, 256, 0, stream>>>(node_types, offT, tmpT, nperm, inv, N_NODES);
    k_hist_edges<<<(E_EDGES+255)/256, 256, 0, stream>>>(edst, inv, deg, E_EDGES);
    k_scan<<<1, 1024, 0, stream>>>(deg, off, N_NODES);
    k_scatter_edges<<<(E_EDGES+255)/256, 256, 0, stream>>>(esrc, edst, edge_types, inv, off, tmpN, epk, E_EDGES);
    k_transpose_rmsg<<<(2*RR*HH*DKK*DKK+255)/256, 256, 0, stream>>>(rel_msg, rmT);
    // weight convert+transpose to bf16 [mat][col][k]
    k_cvt_w<<<(TT*IN_DIM*HID+255)/256, 256, 0, stream>>>(W_adapt, Wta, IN_DIM, HID, TT*IN_DIM*HID);
    k_cvt_w<<<(2*TT*HID*HID+255)/256, 256, 0, stream>>>(Wk, Wtk, HID, HID, 2*TT*HID*HID);
    k_cvt_w<<<(2*TT*HID*HID+255)/256, 256, 0, stream>>>(Wq, Wtq, HID, HID, 2*TT*HID*HID);
    k_cvt_w<<<(2*TT*HID*HID+255)/256, 256, 0, stream>>>(Wv, Wtv, HID, HID, 2*TT*HID*HID);
    k_cvt_w<<<(2*TT*HID*HID+255)/256, 256, 0, stream>>>(Wa, Wtao, HID, HID, 2*TT*HID*HID);

    dim3 gg((N_NODES+63)/64, TT);
    k_adapt<<<gg, 256, 0, stream>>>(x, Wta, b_adapt, nperm, offT, cntT, hp);

    for (int l = 0; l < 2; ++l){
        const size_t WOFF = (size_t)l*TT*HID*HID;
        const size_t BOFF = (size_t)l*TT*HID;
        k_kqv<<<gg, 256, 0, stream>>>(hp, Wtk+WOFF, bk+BOFF, Wtq+WOFF, bq+BOFF, Wtv+WOFF, bv+BOFF,
                                      offT, cntT, Qp, KVpf);
        k_attn<<<(N_NODES+7)/8, 256, 0, stream>>>(Qp, (const float4*)KVpf,
            rel_att + (size_t)l*RR*HH*DKK*DKK,
            rmT + (size_t)l*RR*HH*DKK*DKK,
            rel_pri + (size_t)l*RR*HH,
            off, epk, aggp);
        if (l == 0)
            k_out<true><<<gg, 256, 0, stream>>>(aggp, Wtao+WOFF, ba+BOFF, hp, skip + l*TT,
                                                ln_g, ln_b, nperm, offT, cntT, hp);
        else
            k_out<false><<<gg, 256, 0, stream>>>(aggp, Wtao+WOFF, ba+BOFF, hp, skip + l*TT,
                                                 ln_g, ln_b, nperm, offT, cntT, out);
    }
}

// Round 6
// 1610.717 us; speedup vs baseline: 1.6081x; 1.0601x over previous
//
#include <hip/hip_runtime.h>
#include <math.h>

#define N_NODES 50000
#define E_EDGES 400000
#define IN_DIM  256
#define HID     128
#define TT      3
#define RR      4
#define HH      8
#define DKK     16

typedef __attribute__((ext_vector_type(8))) short bf16x8;
typedef __attribute__((ext_vector_type(4))) float f32x4;

__device__ __forceinline__ float geluf(float v){
    return 0.5f * v * (1.f + erff(v * 0.70710678118654752440f));
}

__device__ __forceinline__ unsigned short f2bf(float f){
    union { float f; unsigned u; } v; v.f = f;
    unsigned r = v.u + 0x7FFF + ((v.u >> 16) & 1);   // round-to-nearest-even
    return (unsigned short)(r >> 16);
}

__device__ __forceinline__ float bf2f(unsigned short u){
    union { unsigned u; float f; } v; v.u = ((unsigned)u) << 16; return v.f;
}

__device__ __forceinline__ bf16x8 cvt8(float4 a, float4 b){
    bf16x8 v;
    v[0]=(short)f2bf(a.x); v[1]=(short)f2bf(a.y); v[2]=(short)f2bf(a.z); v[3]=(short)f2bf(a.w);
    v[4]=(short)f2bf(b.x); v[5]=(short)f2bf(b.y); v[6]=(short)f2bf(b.z); v[7]=(short)f2bf(b.w);
    return v;
}

// ---------------- setup kernels ----------------

__global__ void k_hist_nodes(const int* __restrict__ nt, int* __restrict__ cntT, int n){
    int i = blockIdx.x*blockDim.x + threadIdx.x;
    if (i < n) atomicAdd(&cntT[nt[i]], 1);
}

__global__ void k_offT(const int* __restrict__ cntT, int* __restrict__ offT){
    if (threadIdx.x == 0 && blockIdx.x == 0){
        int a = 0;
        for (int t = 0; t < TT; ++t){ offT[t] = a; a += cntT[t]; }
        offT[TT] = a;
    }
}

__global__ void k_scatter_nodes(const int* __restrict__ nt, const int* __restrict__ offT,
                                int* __restrict__ tmpT, int* __restrict__ nperm,
                                int* __restrict__ inv, int n){
    int i = blockIdx.x*blockDim.x + threadIdx.x;
    if (i < n){
        int t = nt[i];
        int p = offT[t] + atomicAdd(&tmpT[t], 1);
        nperm[p] = i;
        inv[i] = p;
    }
}

// xp[p] = x[nperm[p]] : coalesced row copy (4 rows / 256-thr block)
__global__ __launch_bounds__(256) void k_permute_x(const float* __restrict__ x,
                                                   const int* __restrict__ nperm,
                                                   float* __restrict__ xp){
    int row = blockIdx.x*4 + (threadIdx.x >> 6);
    if (row >= N_NODES) return;
    int src = nperm[row];
    int c = (threadIdx.x & 63) * 4;
    *(float4*)&xp[(size_t)row*IN_DIM + c] = *(const float4*)&x[(size_t)src*IN_DIM + c];
}

// degree histogram over PERMUTED dst ids
__global__ void k_hist_edges(const int* __restrict__ edst, const int* __restrict__ inv,
                             int* __restrict__ deg, int e){
    int i = blockIdx.x*blockDim.x + threadIdx.x;
    if (i < e) atomicAdd(&deg[inv[edst[i]]], 1);
}

__global__ void k_scan(const int* __restrict__ deg, int* __restrict__ off, int n){
    __shared__ int sums[1024];
    int tid = threadIdx.x;
    int chunk = (n + 1023) >> 10;
    int st = tid*chunk, en = st + chunk; if (en > n) en = n;
    int s = 0;
    for (int i = st; i < en; ++i) s += deg[i];
    sums[tid] = s;
    __syncthreads();
    for (int o = 1; o < 1024; o <<= 1){
        int v = (tid >= o) ? sums[tid-o] : 0;
        __syncthreads();
        sums[tid] += v;
        __syncthreads();
    }
    int run = (tid == 0) ? 0 : sums[tid-1];
    for (int i = st; i < en; ++i){ off[i] = run; run += deg[i]; }
    if (tid == 1023) off[n] = run;
}

// sorted packed edges in permuted space: epk[p] = psrc | (type<<16)
__global__ void k_scatter_edges(const int* __restrict__ esrc, const int* __restrict__ edst,
                                const int* __restrict__ ety, const int* __restrict__ inv,
                                const int* __restrict__ off, int* __restrict__ tmpN,
                                int* __restrict__ epk, int e){
    int i = blockIdx.x*blockDim.x + threadIdx.x;
    if (i < e){
        int d = inv[edst[i]];
        int p = off[d] + atomicAdd(&tmpN[d], 1);
        epk[p] = inv[esrc[i]] | (ety[i] << 16);
    }
}

// rel_msg [2][R][H][d][f] -> rmT [2][R][H][f][d]
__global__ void k_transpose_rmsg(const float* __restrict__ rm, float* __restrict__ rmT){
    int i = blockIdx.x*blockDim.x + threadIdx.x;
    const int tot = 2*RR*HH*DKK*DKK;
    if (i < tot){
        int f = i & 15;
        int d = (i >> 4) & 15;
        int rest = i >> 8;
        rmT[(rest*DKK + f)*DKK + d] = rm[i];
    }
}

// convert fp32 weights [mat][K][N] -> bf16 transposed [mat][N][K]
__global__ void k_cvt_w(const float* __restrict__ src, short* __restrict__ dst,
                        int K, int N, int total){
    int i = blockIdx.x*256 + threadIdx.x;
    if (i >= total) return;
    int mat = i / (K*N);
    int rem = i - mat*K*N;
    int k = rem / N, c = rem - k*N;
    dst[(size_t)mat*K*N + (size_t)c*K + k] = (short)f2bf(src[i]);
}

// ---------------- MFMA GEMM building blocks ----------------
// block: 64 rows x 128 cols, 256 thr / 4 waves; wave tile 64x32 (4m x 2n).
// LDS: Asw[64][128] bf16 swizzled, Bsw[128][128] bf16 swizzled (slot ^= row&7).

#define STAGE_B(WT, KTOT, KC) \
  for (int i_ = tid; i_ < 128*16; i_ += 256){ \
    int colb = i_ >> 4, slot = i_ & 15; \
    bf16x8 v_ = *(const bf16x8*)&(WT)[(size_t)colb*(KTOT) + (KC) + slot*8]; \
    *(bf16x8*)&Bsw[(colb*16 + (slot ^ (colb&7)))*8] = v_; \
  }

#define MFMA_CORE(ACC) \
  _Pragma("unroll") \
  for (int kk8 = 0; kk8 < 16; kk8 += 4){ \
    int ks = kk8 + kq; \
    bf16x8 afr[4]; bf16x8 bfr[2]; \
    _Pragma("unroll") for (int m_=0;m_<4;++m_) \
      afr[m_] = *(bf16x8*)&Asw[((m_*16+wl)*16 + (ks ^ wl7))*8]; \
    _Pragma("unroll") for (int n_=0;n_<2;++n_) \
      bfr[n_] = *(bf16x8*)&Bsw[((wv*32+n_*16+wl)*16 + (ks ^ wl7))*8]; \
    _Pragma("unroll") for (int m_=0;m_<4;++m_) \
      _Pragma("unroll") for (int n_=0;n_<2;++n_) \
        ACC[m_][n_] = __builtin_amdgcn_mfma_f32_16x16x32_bf16(afr[m_], bfr[n_], ACC[m_][n_], 0, 0, 0); \
  }

#define ZERO_ACC(ACC) \
  _Pragma("unroll") for (int m_=0;m_<4;++m_) \
    _Pragma("unroll") for (int n_=0;n_<2;++n_) \
      ACC[m_][n_] = (f32x4){0.f,0.f,0.f,0.f};

// ---------------- adapt: hp = tanh(xp @ W_adapt[t] + b), K=256, linear A ----------------

__global__ __launch_bounds__(256) void k_adapt(
    const float* __restrict__ xp, const short* __restrict__ Wta, const float* __restrict__ b_,
    const int* __restrict__ offT, const int* __restrict__ cntT,
    float* __restrict__ hp)
{
    const int t = blockIdx.y;
    const int cnt = cntT[t];
    const int base = blockIdx.x * 64;
    if (base >= cnt) return;
    const int gbase = offT[t] + base;
    __shared__ short Asw[64*128];
    __shared__ short Bsw[128*128];
    const int tid = threadIdx.x;
    const int lane = tid & 63, wv = tid >> 6;
    const int wl = lane & 15, kq = lane >> 4, wl7 = wl & 7;
    const short* Wt = Wta + (size_t)t*HID*IN_DIM;

    f32x4 acc[4][2];
    ZERO_ACC(acc)
    for (int kc = 0; kc < IN_DIM; kc += 128){
        for (int i_ = tid; i_ < 64*16; i_ += 256){
            int rowa = i_ >> 4, slot = i_ & 15;
            int grow = gbase + rowa; if (grow > N_NODES-1) grow = N_NODES-1;
            const float* sp = xp + (size_t)grow*IN_DIM + kc + slot*8;
            *(bf16x8*)&Asw[(rowa*16 + (slot ^ (rowa&7)))*8] = cvt8(*(const float4*)sp, *(const float4*)(sp+4));
        }
        STAGE_B(Wt, IN_DIM, kc)
        __syncthreads();
        MFMA_CORE(acc)
        __syncthreads();
    }
#pragma unroll
    for (int n = 0; n < 2; ++n){
        int col = wv*32 + n*16 + wl;
        float bb = b_[t*HID + col];
#pragma unroll
        for (int m = 0; m < 4; ++m){
#pragma unroll
            for (int i = 0; i < 4; ++i){
                int row = m*16 + kq*4 + i;
                if (base + row < cnt)
                    hp[(size_t)(gbase+row)*HID + col] = tanhf(acc[m][n][i] + bb);
            }
        }
    }
}

// ---------------- merged K/Q/V MFMA GEMM ----------------
// A (hp rows, permuted, linear) staged once; 3 weight passes.
// K/V written packed bf16: KVb[(node<<8) + (h*8+jj)*4 + {0,1:K(d0,d0+1) | 2,3:V}]

__global__ __launch_bounds__(256) void k_kqv(
    const float* __restrict__ hp,
    const short* __restrict__ Wtk, const float* __restrict__ bk_,
    const short* __restrict__ Wtq, const float* __restrict__ bq_,
    const short* __restrict__ Wtv, const float* __restrict__ bv_,
    const int* __restrict__ offT, const int* __restrict__ cntT,
    float* __restrict__ Qp, unsigned short* __restrict__ KVb)
{
    const int t = blockIdx.y;
    const int cnt = cntT[t];
    const int base = blockIdx.x * 64;
    if (base >= cnt) return;
    const int gbase = offT[t] + base;
    __shared__ short Asw[64*128];
    __shared__ short Bsw[128*128];
    const int tid = threadIdx.x;
    const int lane = tid & 63, wv = tid >> 6;
    const int wl = lane & 15, kq = lane >> 4, wl7 = wl & 7;

    for (int i_ = tid; i_ < 64*16; i_ += 256){
        int rowa = i_ >> 4, slot = i_ & 15;
        int grow = gbase + rowa; if (grow > N_NODES-1) grow = N_NODES-1;
        const float* sp = hp + (size_t)grow*HID + slot*8;
        *(bf16x8*)&Asw[(rowa*16 + (slot ^ (rowa&7)))*8] = cvt8(*(const float4*)sp, *(const float4*)(sp+4));
    }

    // ---- pass K ----
    {
        const short* Wt = Wtk + (size_t)t*HID*HID;
        STAGE_B(Wt, HID, 0)
        __syncthreads();
        f32x4 acc[4][2]; ZERO_ACC(acc)
        MFMA_CORE(acc)
        __syncthreads();
#pragma unroll
        for (int n = 0; n < 2; ++n){
            int col = wv*32 + n*16 + wl;
            float bb = bk_[t*HID + col];
            int slot = ((col>>4)*8 + ((col&15)>>1))*4 + (col&1);
#pragma unroll
            for (int m = 0; m < 4; ++m){
#pragma unroll
                for (int i = 0; i < 4; ++i){
                    int row = m*16 + kq*4 + i;
                    if (base + row < cnt)
                        KVb[((size_t)(gbase+row)<<8) + slot] = f2bf(acc[m][n][i] + bb);
                }
            }
        }
    }
    // ---- pass Q ----
    {
        const short* Wt = Wtq + (size_t)t*HID*HID;
        STAGE_B(Wt, HID, 0)
        __syncthreads();
        f32x4 acc[4][2]; ZERO_ACC(acc)
        MFMA_CORE(acc)
        __syncthreads();
#pragma unroll
        for (int n = 0; n < 2; ++n){
            int col = wv*32 + n*16 + wl;
            float bb = bq_[t*HID + col];
#pragma unroll
            for (int m = 0; m < 4; ++m){
#pragma unroll
                for (int i = 0; i < 4; ++i){
                    int row = m*16 + kq*4 + i;
                    if (base + row < cnt)
                        Qp[(size_t)(gbase+row)*HID + col] = acc[m][n][i] + bb;
                }
            }
        }
    }
    // ---- pass V ----
    {
        const short* Wt = Wtv + (size_t)t*HID*HID;
        STAGE_B(Wt, HID, 0)
        __syncthreads();
        f32x4 acc[4][2]; ZERO_ACC(acc)
        MFMA_CORE(acc)
        __syncthreads();
#pragma unroll
        for (int n = 0; n < 2; ++n){
            int col = wv*32 + n*16 + wl;
            float bb = bv_[t*HID + col];
            int slot = ((col>>4)*8 + ((col&15)>>1))*4 + (col&1) + 2;
#pragma unroll
            for (int m = 0; m < 4; ++m){
#pragma unroll
                for (int i = 0; i < 4; ++i){
                    int row = m*16 + kq*4 + i;
                    if (base + row < cnt)
                        KVb[((size_t)(gbase+row)<<8) + slot] = f2bf(acc[m][n][i] + bb);
                }
            }
        }
    }
}

// ---------------- per-node attention (bf16 KV, 1-wave workgroups) ----------------
// wave handles 2 nodes; lane = h*8+jj owns dims d0=2jj, d0+1 of head h.
// per-lane edge load: ushort4 {K[d0],K[d0+1],V[d0],V[d0+1]} bf16 (8B).

#define LOADKV4(S, P) \
    int pk##S##0 = epk[(P)+0], pk##S##1 = epk[(P)+1], pk##S##2 = epk[(P)+2], pk##S##3 = epk[(P)+3]; \
    ushort4 kv##S##0 = KVb4[((size_t)(pk##S##0 & 0xFFFF)<<6) + lane]; \
    ushort4 kv##S##1 = KVb4[((size_t)(pk##S##1 & 0xFFFF)<<6) + lane]; \
    ushort4 kv##S##2 = KVb4[((size_t)(pk##S##2 & 0xFFFF)<<6) + lane]; \
    ushort4 kv##S##3 = KVb4[((size_t)(pk##S##3 & 0xFFFF)<<6) + lane];

#define LOGIT_I(S, i) \
    float part##S##i; { \
        int r_ = pk##S##i >> 16; \
        float qa_ = (r_==0)?qa0##S:(r_==1)?qa1##S:(r_==2)?qa2##S:qa3##S; \
        float qb_ = (r_==0)?qb0##S:(r_==1)?qb1##S:(r_==2)?qb2##S:qb3##S; \
        part##S##i = fmaf(bf2f(kv##S##i.x), qa_, bf2f(kv##S##i.y) * qb_); \
    } \
    part##S##i += __shfl_xor(part##S##i, 1); \
    part##S##i += __shfl_xor(part##S##i, 2); \
    part##S##i += __shfl_xor(part##S##i, 4);

#define ACC_I(S, i) { \
    int r_ = pk##S##i >> 16; \
    float e_ = __expf(part##S##i - mn##S); \
    l##S += e_; \
    float vz_ = bf2f(kv##S##i.z), vw_ = bf2f(kv##S##i.w); \
    float w0_=(r_==0)?e_:0.f, w1_=(r_==1)?e_:0.f, w2_=(r_==2)?e_:0.f, w3_=(r_==3)?e_:0.f; \
    cx0##S = fmaf(w0_, vz_, cx0##S); cy0##S = fmaf(w0_, vw_, cy0##S); \
    cx1##S = fmaf(w1_, vz_, cx1##S); cy1##S = fmaf(w1_, vw_, cy1##S); \
    cx2##S = fmaf(w2_, vz_, cx2##S); cy2##S = fmaf(w2_, vw_, cy2##S); \
    cx3##S = fmaf(w3_, vz_, cx3##S); cy3##S = fmaf(w3_, vw_, cy3##S); }

#define BATCH4(S) \
    LOGIT_I(S,0) LOGIT_I(S,1) LOGIT_I(S,2) LOGIT_I(S,3) \
    float bm##S = fmaxf(fmaxf(part##S##0, part##S##1), fmaxf(part##S##2, part##S##3)); \
    float mn##S = fmaxf(m##S, bm##S); \
    float sc##S = __expf(m##S - mn##S); \
    m##S = mn##S; l##S *= sc##S; \
    cx0##S *= sc##S; cx1##S *= sc##S; cx2##S *= sc##S; cx3##S *= sc##S; \
    cy0##S *= sc##S; cy1##S *= sc##S; cy2##S *= sc##S; cy3##S *= sc##S; \
    ACC_I(S,0) ACC_I(S,1) ACC_I(S,2) ACC_I(S,3)

#define TAIL4(S, P, P1) { \
    int pk##S##0 = epk[P]; \
    int pk##S##1 = epk[((P)+1 < (P1)) ? (P)+1 : (P1)-1]; \
    int pk##S##2 = epk[((P)+2 < (P1)) ? (P)+2 : (P1)-1]; \
    int pk##S##3 = epk[((P)+3 < (P1)) ? (P)+3 : (P1)-1]; \
    ushort4 kv##S##0 = KVb4[((size_t)(pk##S##0 & 0xFFFF)<<6) + lane]; \
    ushort4 kv##S##1 = KVb4[((size_t)(pk##S##1 & 0xFFFF)<<6) + lane]; \
    ushort4 kv##S##2 = KVb4[((size_t)(pk##S##2 & 0xFFFF)<<6) + lane]; \
    ushort4 kv##S##3 = KVb4[((size_t)(pk##S##3 & 0xFFFF)<<6) + lane]; \
    LOGIT_I(S,0) LOGIT_I(S,1) LOGIT_I(S,2) LOGIT_I(S,3) \
    if ((P)+1 >= (P1)) part##S##1 = -INFINITY; \
    if ((P)+2 >= (P1)) part##S##2 = -INFINITY; \
    if ((P)+3 >= (P1)) part##S##3 = -INFINITY; \
    float bm##S = fmaxf(fmaxf(part##S##0, part##S##1), fmaxf(part##S##2, part##S##3)); \
    float mn##S = fmaxf(m##S, bm##S); \
    float sc##S = __expf(m##S - mn##S); \
    m##S = mn##S; l##S *= sc##S; \
    cx0##S *= sc##S; cx1##S *= sc##S; cx2##S *= sc##S; cx3##S *= sc##S; \
    cy0##S *= sc##S; cy1##S *= sc##S; cy2##S *= sc##S; cy3##S *= sc##S; \
    ACC_I(S,0) ACC_I(S,1) ACC_I(S,2) ACC_I(S,3) }

#define FINAL2(RIDX) { \
    const float* rm = rmT + (((size_t)((RIDX)*HH + h))*DKK + d0)*DKK; \
    float4 A0 = *(const float4*)(rm + 0),  A1 = *(const float4*)(rm + 4); \
    float4 A2 = *(const float4*)(rm + 8),  A3 = *(const float4*)(rm + 12); \
    float4 B0 = *(const float4*)(rm + 16), B1 = *(const float4*)(rm + 20); \
    float4 B2 = *(const float4*)(rm + 24), B3 = *(const float4*)(rm + 28); \
    float yA[16], yB[16]; \
    _Pragma("unroll") \
    for (int u = 0; u < 8; ++u){ \
        yA[2*u]   = __shfl(cx##RIDX##A, (h<<3) + u); \
        yA[2*u+1] = __shfl(cy##RIDX##A, (h<<3) + u); \
        yB[2*u]   = __shfl(cx##RIDX##B, (h<<3) + u); \
        yB[2*u+1] = __shfl(cy##RIDX##B, (h<<3) + u); \
    } \
    o0A += yA[0]*A0.x + yA[1]*A0.y + yA[2]*A0.z + yA[3]*A0.w \
         + yA[4]*A1.x + yA[5]*A1.y + yA[6]*A1.z + yA[7]*A1.w \
         + yA[8]*A2.x + yA[9]*A2.y + yA[10]*A2.z + yA[11]*A2.w \
         + yA[12]*A3.x + yA[13]*A3.y + yA[14]*A3.z + yA[15]*A3.w; \
    o1A += yA[0]*B0.x + yA[1]*B0.y + yA[2]*B0.z + yA[3]*B0.w \
         + yA[4]*B1.x + yA[5]*B1.y + yA[6]*B1.z + yA[7]*B1.w \
         + yA[8]*B2.x + yA[9]*B2.y + yA[10]*B2.z + yA[11]*B2.w \
         + yA[12]*B3.x + yA[13]*B3.y + yA[14]*B3.z + yA[15]*B3.w; \
    o0B += yB[0]*A0.x + yB[1]*A0.y + yB[2]*A0.z + yB[3]*A0.w \
         + yB[4]*A1.x + yB[5]*A1.y + yB[6]*A1.z + yB[7]*A1.w \
         + yB[8]*A2.x + yB[9]*A2.y + yB[10]*A2.z + yB[11]*A2.w \
         + yB[12]*A3.x + yB[13]*A3.y + yB[14]*A3.z + yB[15]*A3.w; \
    o1B += yB[0]*B0.x + yB[1]*B0.y + yB[2]*B0.z + yB[3]*B0.w \
         + yB[4]*B1.x + yB[5]*B1.y + yB[6]*B1.z + yB[7]*B1.w \
         + yB[8]*B2.x + yB[9]*B2.y + yB[10]*B2.z + yB[11]*B2.w \
         + yB[12]*B3.x + yB[13]*B3.y + yB[14]*B3.z + yB[15]*B3.w; }

__global__ __launch_bounds__(64) void k_attn(
    const float* __restrict__ Qp, const ushort4* __restrict__ KVb4,
    const float* __restrict__ Ratt, const float* __restrict__ rmT,
    const float* __restrict__ pri,
    const int* __restrict__ off, const int* __restrict__ epk,
    float* __restrict__ agg)
{
    const int n0 = blockIdx.x*2;
    if (n0 >= N_NODES) return;
    const bool hasB = (n0 + 1) < N_NODES;
    const int lane = threadIdx.x & 63;
    const int h  = lane >> 3;
    const int d0 = (lane & 7) * 2;

    const float* qpA = Qp + (size_t)n0*HID + h*DKK;
    const float* qpB = Qp + (size_t)(hasB ? n0+1 : n0)*HID + h*DKK;
    float qvA[16], qvB[16];
#pragma unroll
    for (int u = 0; u < 4; ++u){
        float4 ta = *(const float4*)(qpA + 4*u);
        float4 tb = *(const float4*)(qpB + 4*u);
        qvA[4*u+0]=ta.x; qvA[4*u+1]=ta.y; qvA[4*u+2]=ta.z; qvA[4*u+3]=ta.w;
        qvB[4*u+0]=tb.x; qvB[4*u+1]=tb.y; qvB[4*u+2]=tb.z; qvB[4*u+3]=tb.w;
    }

    float qa0A,qa1A,qa2A,qa3A,qb0A,qb1A,qb2A,qb3A;
    float qa0B,qa1B,qa2B,qa3B,qb0B,qb1B,qb2B,qb3B;
#pragma unroll
    for (int r = 0; r < RR; ++r){
        const float* ar = Ratt + (((size_t)(r*HH + h))*DKK + d0)*DKK;
        float s0A=0.f, s1A=0.f, s0B=0.f, s1B=0.f;
#pragma unroll
        for (int u = 0; u < 4; ++u){
            float4 a0 = *(const float4*)(ar + 4*u);
            float4 a1 = *(const float4*)(ar + DKK + 4*u);
            s0A += a0.x*qvA[4*u+0] + a0.y*qvA[4*u+1] + a0.z*qvA[4*u+2] + a0.w*qvA[4*u+3];
            s1A += a1.x*qvA[4*u+0] + a1.y*qvA[4*u+1] + a1.z*qvA[4*u+2] + a1.w*qvA[4*u+3];
            s0B += a0.x*qvB[4*u+0] + a0.y*qvB[4*u+1] + a0.z*qvB[4*u+2] + a0.w*qvB[4*u+3];
            s1B += a1.x*qvB[4*u+0] + a1.y*qvB[4*u+1] + a1.z*qvB[4*u+2] + a1.w*qvB[4*u+3];
        }
        float pr = pri[r*HH + h] * 0.25f;
        s0A *= pr; s1A *= pr; s0B *= pr; s1B *= pr;
        if      (r == 0){ qa0A=s0A; qb0A=s1A; qa0B=s0B; qb0B=s1B; }
        else if (r == 1){ qa1A=s0A; qb1A=s1A; qa1B=s0B; qb1B=s1B; }
        else if (r == 2){ qa2A=s0A; qb2A=s1A; qa2B=s0B; qb2B=s1B; }
        else            { qa3A=s0A; qb3A=s1A; qa3B=s0B; qb3B=s1B; }
    }

    float mA=-INFINITY, lA=0.f, cx0A=0.f,cx1A=0.f,cx2A=0.f,cx3A=0.f, cy0A=0.f,cy1A=0.f,cy2A=0.f,cy3A=0.f;
    float mB=-INFINITY, lB=0.f, cx0B=0.f,cx1B=0.f,cx2B=0.f,cx3B=0.f, cy0B=0.f,cy1B=0.f,cy2B=0.f,cy3B=0.f;

    int pa = off[n0],  ea = off[n0+1];
    int pb = 0, eb = 0;
    if (hasB){ pb = ea; eb = off[n0+2]; }

    while (pa + 4 <= ea && pb + 4 <= eb){
        LOADKV4(A, pa)
        LOADKV4(B, pb)
        BATCH4(A)
        BATCH4(B)
        pa += 4; pb += 4;
    }
    while (pa + 4 <= ea){
        LOADKV4(A, pa)
        BATCH4(A)
        pa += 4;
    }
    while (pb + 4 <= eb){
        LOADKV4(B, pb)
        BATCH4(B)
        pb += 4;
    }
    if (pa < ea) TAIL4(A, pa, ea)
    if (pb < eb) TAIL4(B, pb, eb)

    float o0A=0.f, o1A=0.f, o0B=0.f, o1B=0.f;
    FINAL2(0)
    FINAL2(1)
    FINAL2(2)
    FINAL2(3)

    const float invA = 1.f / fmaxf(lA, 1e-9f);
    *(float2*)(agg + (size_t)n0*HID + h*DKK + d0) = make_float2(o0A*invA, o1A*invA);
    if (hasB){
        const float invB = 1.f / fmaxf(lB, 1e-9f);
        *(float2*)(agg + (size_t)(n0+1)*HID + h*DKK + d0) = make_float2(o0B*invB, o1B*invB);
    }
}

// ---------------- output MFMA GEMM: gelu(aggp) @ Wa + blend (+LN+ReLU) ----------------

template<bool USE_LN>
__global__ __launch_bounds__(256) void k_out(
    const float* __restrict__ aggp, const short* __restrict__ Wta, const float* __restrict__ ba_,
    const float* __restrict__ hin, const float* __restrict__ skipl,
    const float* __restrict__ gam, const float* __restrict__ bet,
    const int* __restrict__ nperm, const int* __restrict__ offT, const int* __restrict__ cntT,
    float* __restrict__ hout)
{
    const int t = blockIdx.y;
    const int cnt = cntT[t];
    const int base = blockIdx.x * 64;
    if (base >= cnt) return;
    const int gbase = offT[t] + base;
    __shared__ short Asw[64*128];
    __shared__ short Bsw[128*128];
    __shared__ int nid[64];
    const int tid = threadIdx.x;
    if (!USE_LN && tid < 64){
        int ii = base + tid;
        nid[tid] = (ii < cnt) ? nperm[offT[t] + ii] : -1;
    }
    const int lane = tid & 63, wv = tid >> 6;
    const int wl = lane & 15, kq = lane >> 4, wl7 = wl & 7;

    for (int i_ = tid; i_ < 64*16; i_ += 256){
        int rowa = i_ >> 4, slot = i_ & 15;
        int grow = gbase + rowa; if (grow > N_NODES-1) grow = N_NODES-1;
        const float* sp = aggp + (size_t)grow*HID + slot*8;
        float4 f0 = *(const float4*)sp, f1 = *(const float4*)(sp+4);
        f0.x=geluf(f0.x); f0.y=geluf(f0.y); f0.z=geluf(f0.z); f0.w=geluf(f0.w);
        f1.x=geluf(f1.x); f1.y=geluf(f1.y); f1.z=geluf(f1.z); f1.w=geluf(f1.w);
        *(bf16x8*)&Asw[(rowa*16 + (slot ^ (rowa&7)))*8] = cvt8(f0, f1);
    }
    {
        const short* Wt = Wta + (size_t)t*HID*HID;
        STAGE_B(Wt, HID, 0)
    }
    __syncthreads();
    f32x4 acc[4][2]; ZERO_ACC(acc)
    MFMA_CORE(acc)
    __syncthreads();

    float* smemf = (float*)Bsw;
#pragma unroll
    for (int n = 0; n < 2; ++n){
        int col = wv*32 + n*16 + wl;
#pragma unroll
        for (int m = 0; m < 4; ++m){
#pragma unroll
            for (int i = 0; i < 4; ++i){
                int row = m*16 + kq*4 + i;
                smemf[row*128 + col] = acc[m][n][i];
            }
        }
    }
    __syncthreads();

    const float alpha = 1.f / (1.f + __expf(-skipl[t]));
    const float onem = 1.f - alpha;
    const int row = tid >> 2;
    const int part = tid & 3;
    const int cbase = part * 32;
    float vals[32];
    float s = 0.f, s2 = 0.f;
    int growr = gbase + row; if (growr > N_NODES-1) growr = N_NODES-1;
#pragma unroll
    for (int u = 0; u < 8; ++u){
        float4 d  = *(float4*)&smemf[row*128 + cbase + u*4];
        float4 bb = *(const float4*)&ba_[t*HID + cbase + u*4];
        float4 hv = *(const float4*)&hin[(size_t)growr*HID + cbase + u*4];
        float v0 = (d.x + bb.x)*alpha + hv.x*onem;
        float v1 = (d.y + bb.y)*alpha + hv.y*onem;
        float v2 = (d.z + bb.z)*alpha + hv.z*onem;
        float v3 = (d.w + bb.w)*alpha + hv.w*onem;
        vals[u*4+0]=v0; vals[u*4+1]=v1; vals[u*4+2]=v2; vals[u*4+3]=v3;
        s += v0+v1+v2+v3;
        s2 += v0*v0+v1*v1+v2*v2+v3*v3;
    }
    if (USE_LN){
        s  += __shfl_xor(s, 1);  s  += __shfl_xor(s, 2);
        s2 += __shfl_xor(s2, 1); s2 += __shfl_xor(s2, 2);
        float mu = s * (1.f/128.f);
        float var = s2 * (1.f/128.f) - mu*mu;
        float rstd = rsqrtf(var + 1e-5f);
        if (base + row < cnt){
#pragma unroll
            for (int u = 0; u < 8; ++u){
                float4 g4 = *(const float4*)&gam[t*HID + cbase + u*4];
                float4 e4 = *(const float4*)&bet[t*HID + cbase + u*4];
                float4 r4;
                r4.x = fmaxf((vals[u*4+0]-mu)*rstd*g4.x + e4.x, 0.f);
                r4.y = fmaxf((vals[u*4+1]-mu)*rstd*g4.y + e4.y, 0.f);
                r4.z = fmaxf((vals[u*4+2]-mu)*rstd*g4.z + e4.z, 0.f);
                r4.w = fmaxf((vals[u*4+3]-mu)*rstd*g4.w + e4.w, 0.f);
                *(float4*)&hout[(size_t)(gbase+row)*HID + cbase + u*4] = r4;
            }
        }
    } else {
        __syncthreads();
        int node = (base + row < cnt) ? nid[row] : -1;
        if (node >= 0){
#pragma unroll
            for (int u = 0; u < 8; ++u){
                float4 r4 = make_float4(vals[u*4+0], vals[u*4+1], vals[u*4+2], vals[u*4+3]);
                *(float4*)&hout[(size_t)node*HID + cbase + u*4] = r4;
            }
        }
    }
}

// ---------------- launch ----------------

extern "C" void kernel_launch(void* const* d_in, const int* in_sizes, int n_in,
                              void* d_out, int out_size, void* d_ws, size_t ws_size,
                              hipStream_t stream)
{
    const float* x         = (const float*)d_in[0];
    const int*   node_types= (const int*)  d_in[1];
    const int*   edge_index= (const int*)  d_in[2];
    const int*   edge_types= (const int*)  d_in[3];
    const float* W_adapt   = (const float*)d_in[4];
    const float* b_adapt   = (const float*)d_in[5];
    const float* Wk        = (const float*)d_in[6];
    const float* bk        = (const float*)d_in[7];
    const float* Wq        = (const float*)d_in[8];
    const float* bq        = (const float*)d_in[9];
    const float* Wv        = (const float*)d_in[10];
    const float* bv        = (const float*)d_in[11];
    const float* Wa        = (const float*)d_in[12];
    const float* ba        = (const float*)d_in[13];
    const float* rel_pri   = (const float*)d_in[14];
    const float* rel_att   = (const float*)d_in[15];
    const float* rel_msg   = (const float*)d_in[16];
    const float* skip      = (const float*)d_in[17];
    const float* ln_g      = (const float*)d_in[18];
    const float* ln_b      = (const float*)d_in[19];
    float* out = (float*)d_out;

    char* p = (char*)d_ws;
    auto alloc = [&](size_t bytes) -> void* {
        void* q = (void*)p;
        p += (bytes + 255) & ~(size_t)255;
        return q;
    };
    float* xp    = (float*)alloc((size_t)N_NODES*IN_DIM*4);
    float* hp    = (float*)alloc((size_t)N_NODES*HID*4);
    float* Qp    = (float*)alloc((size_t)N_NODES*HID*4);
    unsigned short* KVb = (unsigned short*)alloc((size_t)N_NODES*256*2);
    float* aggp  = (float*)alloc((size_t)N_NODES*HID*4);
    float* rmT   = (float*)alloc((size_t)2*RR*HH*DKK*DKK*4);
    short* Wta   = (short*)alloc((size_t)TT*IN_DIM*HID*2);
    short* Wtk   = (short*)alloc((size_t)2*TT*HID*HID*2);
    short* Wtq   = (short*)alloc((size_t)2*TT*HID*HID*2);
    short* Wtv   = (short*)alloc((size_t)2*TT*HID*HID*2);
    short* Wtao  = (short*)alloc((size_t)2*TT*HID*HID*2);
    int* ib      = (int*)alloc((size_t)(2*N_NODES + 8)*4);
    int* deg  = ib;
    int* tmpN = ib + N_NODES;
    int* cntT = ib + 2*N_NODES;
    int* tmpT = ib + 2*N_NODES + 4;
    int* off   = (int*)alloc((size_t)(N_NODES+1)*4);
    int* offT  = (int*)alloc(16);
    int* epk   = (int*)alloc((size_t)E_EDGES*4);
    int* nperm = (int*)alloc((size_t)N_NODES*4);
    int* inv   = (int*)alloc((size_t)N_NODES*4);

    const int* esrc = edge_index;
    const int* edst = edge_index + E_EDGES;

    hipMemsetAsync(ib, 0, (size_t)(2*N_NODES + 8)*4, stream);
    k_hist_nodes<<<(N_NODES+255)/256, 256, 0, stream>>>(node_types, cntT, N_NODES);
    k_offT<<<1, 1, 0, stream>>>(cntT, offT);
    k_scatter_nodes<<<(N_NODES+255)/256, 256, 0, stream>>>(node_types, offT, tmpT, nperm, inv, N_NODES);
    k_permute_x<<<(N_NODES+3)/4, 256, 0, stream>>>(x, nperm, xp);
    k_hist_edges<<<(E_EDGES+255)/256, 256, 0, stream>>>(edst, inv, deg, E_EDGES);
    k_scan<<<1, 1024, 0, stream>>>(deg, off, N_NODES);
    k_scatter_edges<<<(E_EDGES+255)/256, 256, 0, stream>>>(esrc, edst, edge_types, inv, off, tmpN, epk, E_EDGES);
    k_transpose_rmsg<<<(2*RR*HH*DKK*DKK+255)/256, 256, 0, stream>>>(rel_msg, rmT);
    k_cvt_w<<<(TT*IN_DIM*HID+255)/256, 256, 0, stream>>>(W_adapt, Wta, IN_DIM, HID, TT*IN_DIM*HID);
    k_cvt_w<<<(2*TT*HID*HID+255)/256, 256, 0, stream>>>(Wk, Wtk, HID, HID, 2*TT*HID*HID);
    k_cvt_w<<<(2*TT*HID*HID+255)/256, 256, 0, stream>>>(Wq, Wtq, HID, HID, 2*TT*HID*HID);
    k_cvt_w<<<(2*TT*HID*HID+255)/256, 256, 0, stream>>>(Wv, Wtv, HID, HID, 2*TT*HID*HID);
    k_cvt_w<<<(2*TT*HID*HID+255)/256, 256, 0, stream>>>(Wa, Wtao, HID, HID, 2*TT*HID*HID);

    dim3 gg((N_NODES+63)/64, TT);
    k_adapt<<<gg, 256, 0, stream>>>(xp, Wta, b_adapt, offT, cntT, hp);

    for (int l = 0; l < 2; ++l){
        const size_t WOFF = (size_t)l*TT*HID*HID;
        const size_t BOFF = (size_t)l*TT*HID;
        k_kqv<<<gg, 256, 0, stream>>>(hp, Wtk+WOFF, bk+BOFF, Wtq+WOFF, bq+BOFF, Wtv+WOFF, bv+BOFF,
                                      offT, cntT, Qp, KVb);
        k_attn<<<(N_NODES+1)/2, 64, 0, stream>>>(Qp, (const ushort4*)KVb,
            rel_att + (size_t)l*RR*HH*DKK*DKK,
            rmT + (size_t)l*RR*HH*DKK*DKK,
            rel_pri + (size_t)l*RR*HH,
            off, epk, aggp);
        if (l == 0)
            k_out<true><<<gg, 256, 0, stream>>>(aggp, Wtao+WOFF, ba+BOFF, hp, skip + l*TT,
                                                ln_g, ln_b, nperm, offT, cntT, hp);
        else
            k_out<false><<<gg, 256, 0, stream>>>(aggp, Wtao+WOFF, ba+BOFF, hp, skip + l*TT,
                                                 ln_g, ln_b, nperm, offT, cntT, out);
    }
}

// Round 7
// 1021.658 us; speedup vs baseline: 2.5353x; 1.5766x over previous
//
#include <hip/hip_runtime.h>
#include <math.h>

#define N_NODES 50000
#define E_EDGES 400000
#define IN_DIM  256
#define HID     128
#define TT      3
#define RR      4
#define HH      8
#define DKK     16

typedef __attribute__((ext_vector_type(8))) short bf16x8;
typedef __attribute__((ext_vector_type(4))) float f32x4;

__device__ __forceinline__ float geluf(float v){
    return 0.5f * v * (1.f + erff(v * 0.70710678118654752440f));
}

__device__ __forceinline__ unsigned short f2bf(float f){
    union { float f; unsigned u; } v; v.f = f;
    unsigned r = v.u + 0x7FFF + ((v.u >> 16) & 1);   // round-to-nearest-even
    return (unsigned short)(r >> 16);
}

__device__ __forceinline__ float bf2f(unsigned short u){
    union { unsigned u; float f; } v; v.u = ((unsigned)u) << 16; return v.f;
}

__device__ __forceinline__ bf16x8 cvt8(float4 a, float4 b){
    bf16x8 v;
    v[0]=(short)f2bf(a.x); v[1]=(short)f2bf(a.y); v[2]=(short)f2bf(a.z); v[3]=(short)f2bf(a.w);
    v[4]=(short)f2bf(b.x); v[5]=(short)f2bf(b.y); v[6]=(short)f2bf(b.z); v[7]=(short)f2bf(b.w);
    return v;
}

// ---------------- setup kernels ----------------
// wave-aggregated histogram: 3 leader-atomics per wave instead of 64 lane-atomics
// (50k atomics on 3 addresses serialized at ~6.3ns each = 317us — G12 fix)

__global__ void k_hist_nodes(const int* __restrict__ nt, int* __restrict__ cntT, int n){
    int i = blockIdx.x*blockDim.x + threadIdx.x;
    int t = (i < n) ? nt[i] : -1;
#pragma unroll
    for (int tt = 0; tt < TT; ++tt){
        unsigned long long m = __ballot(t == tt);
        int lane = threadIdx.x & 63;
        if (m != 0ull){
            int leader = __ffsll((long long)m) - 1;
            if (lane == leader) atomicAdd(&cntT[tt], __popcll(m));
        }
    }
}

__global__ void k_offT(const int* __restrict__ cntT, int* __restrict__ offT){
    if (threadIdx.x == 0 && blockIdx.x == 0){
        int a = 0;
        for (int t = 0; t < TT; ++t){ offT[t] = a; a += cntT[t]; }
        offT[TT] = a;
    }
}

// wave-aggregated scatter: leader atomic per (wave,type), intra-wave rank via ballot
__global__ void k_scatter_nodes(const int* __restrict__ nt, const int* __restrict__ offT,
                                int* __restrict__ tmpT, int* __restrict__ nperm,
                                int* __restrict__ inv, int n){
    int i = blockIdx.x*blockDim.x + threadIdx.x;
    int t = (i < n) ? nt[i] : -1;
    int lane = threadIdx.x & 63;
    unsigned long long lt = (lane == 0) ? 0ull : ((1ull << lane) - 1ull);
#pragma unroll
    for (int tt = 0; tt < TT; ++tt){
        unsigned long long m = __ballot(t == tt);
        if (m == 0ull) continue;
        int leader = __ffsll((long long)m) - 1;
        int base = 0;
        if (lane == leader) base = atomicAdd(&tmpT[tt], __popcll(m));
        base = __shfl(base, leader);
        if (t == tt){
            int p = offT[tt] + base + (int)__popcll(m & lt);
            nperm[p] = i;
            inv[i] = p;
        }
    }
}

// xp[p] = x[nperm[p]] : coalesced row copy (4 rows / 256-thr block)
__global__ __launch_bounds__(256) void k_permute_x(const float* __restrict__ x,
                                                   const int* __restrict__ nperm,
                                                   float* __restrict__ xp){
    int row = blockIdx.x*4 + (threadIdx.x >> 6);
    if (row >= N_NODES) return;
    int src = nperm[row];
    int c = (threadIdx.x & 63) * 4;
    *(float4*)&xp[(size_t)row*IN_DIM + c] = *(const float4*)&x[(size_t)src*IN_DIM + c];
}

// degree histogram over PERMUTED dst ids (50k addresses, low contention — keep)
__global__ void k_hist_edges(const int* __restrict__ edst, const int* __restrict__ inv,
                             int* __restrict__ deg, int e){
    int i = blockIdx.x*blockDim.x + threadIdx.x;
    if (i < e) atomicAdd(&deg[inv[edst[i]]], 1);
}

__global__ void k_scan(const int* __restrict__ deg, int* __restrict__ off, int n){
    __shared__ int sums[1024];
    int tid = threadIdx.x;
    int chunk = (n + 1023) >> 10;
    int st = tid*chunk, en = st + chunk; if (en > n) en = n;
    int s = 0;
    for (int i = st; i < en; ++i) s += deg[i];
    sums[tid] = s;
    __syncthreads();
    for (int o = 1; o < 1024; o <<= 1){
        int v = (tid >= o) ? sums[tid-o] : 0;
        __syncthreads();
        sums[tid] += v;
        __syncthreads();
    }
    int run = (tid == 0) ? 0 : sums[tid-1];
    for (int i = st; i < en; ++i){ off[i] = run; run += deg[i]; }
    if (tid == 1023) off[n] = run;
}

// sorted packed edges in permuted space: epk[p] = psrc | (type<<16)
__global__ void k_scatter_edges(const int* __restrict__ esrc, const int* __restrict__ edst,
                                const int* __restrict__ ety, const int* __restrict__ inv,
                                const int* __restrict__ off, int* __restrict__ tmpN,
                                int* __restrict__ epk, int e){
    int i = blockIdx.x*blockDim.x + threadIdx.x;
    if (i < e){
        int d = inv[edst[i]];
        int p = off[d] + atomicAdd(&tmpN[d], 1);
        epk[p] = inv[esrc[i]] | (ety[i] << 16);
    }
}

// rel_msg [2][R][H][d][f] -> rmT [2][R][H][f][d]
__global__ void k_transpose_rmsg(const float* __restrict__ rm, float* __restrict__ rmT){
    int i = blockIdx.x*blockDim.x + threadIdx.x;
    const int tot = 2*RR*HH*DKK*DKK;
    if (i < tot){
        int f = i & 15;
        int d = (i >> 4) & 15;
        int rest = i >> 8;
        rmT[(rest*DKK + f)*DKK + d] = rm[i];
    }
}

// convert fp32 weights [mat][K][N] -> bf16 transposed [mat][N][K]
__global__ void k_cvt_w(const float* __restrict__ src, short* __restrict__ dst,
                        int K, int N, int total){
    int i = blockIdx.x*256 + threadIdx.x;
    if (i >= total) return;
    int mat = i / (K*N);
    int rem = i - mat*K*N;
    int k = rem / N, c = rem - k*N;
    dst[(size_t)mat*K*N + (size_t)c*K + k] = (short)f2bf(src[i]);
}

// ---------------- MFMA GEMM building blocks ----------------
// block: 64 rows x 128 cols, 256 thr / 4 waves; wave tile 64x32 (4m x 2n).
// LDS: Asw[64][128] bf16 swizzled, Bsw[128][128] bf16 swizzled (slot ^= row&7).

#define STAGE_B(WT, KTOT, KC) \
  for (int i_ = tid; i_ < 128*16; i_ += 256){ \
    int colb = i_ >> 4, slot = i_ & 15; \
    bf16x8 v_ = *(const bf16x8*)&(WT)[(size_t)colb*(KTOT) + (KC) + slot*8]; \
    *(bf16x8*)&Bsw[(colb*16 + (slot ^ (colb&7)))*8] = v_; \
  }

#define MFMA_CORE(ACC) \
  _Pragma("unroll") \
  for (int kk8 = 0; kk8 < 16; kk8 += 4){ \
    int ks = kk8 + kq; \
    bf16x8 afr[4]; bf16x8 bfr[2]; \
    _Pragma("unroll") for (int m_=0;m_<4;++m_) \
      afr[m_] = *(bf16x8*)&Asw[((m_*16+wl)*16 + (ks ^ wl7))*8]; \
    _Pragma("unroll") for (int n_=0;n_<2;++n_) \
      bfr[n_] = *(bf16x8*)&Bsw[((wv*32+n_*16+wl)*16 + (ks ^ wl7))*8]; \
    _Pragma("unroll") for (int m_=0;m_<4;++m_) \
      _Pragma("unroll") for (int n_=0;n_<2;++n_) \
        ACC[m_][n_] = __builtin_amdgcn_mfma_f32_16x16x32_bf16(afr[m_], bfr[n_], ACC[m_][n_], 0, 0, 0); \
  }

#define ZERO_ACC(ACC) \
  _Pragma("unroll") for (int m_=0;m_<4;++m_) \
    _Pragma("unroll") for (int n_=0;n_<2;++n_) \
      ACC[m_][n_] = (f32x4){0.f,0.f,0.f,0.f};

// ---------------- adapt: hp = tanh(xp @ W_adapt[t] + b), K=256, linear A ----------------

__global__ __launch_bounds__(256) void k_adapt(
    const float* __restrict__ xp, const short* __restrict__ Wta, const float* __restrict__ b_,
    const int* __restrict__ offT, const int* __restrict__ cntT,
    float* __restrict__ hp)
{
    const int t = blockIdx.y;
    const int cnt = cntT[t];
    const int base = blockIdx.x * 64;
    if (base >= cnt) return;
    const int gbase = offT[t] + base;
    __shared__ short Asw[64*128];
    __shared__ short Bsw[128*128];
    const int tid = threadIdx.x;
    const int lane = tid & 63, wv = tid >> 6;
    const int wl = lane & 15, kq = lane >> 4, wl7 = wl & 7;
    const short* Wt = Wta + (size_t)t*HID*IN_DIM;

    f32x4 acc[4][2];
    ZERO_ACC(acc)
    for (int kc = 0; kc < IN_DIM; kc += 128){
        for (int i_ = tid; i_ < 64*16; i_ += 256){
            int rowa = i_ >> 4, slot = i_ & 15;
            int grow = gbase + rowa; if (grow > N_NODES-1) grow = N_NODES-1;
            const float* sp = xp + (size_t)grow*IN_DIM + kc + slot*8;
            *(bf16x8*)&Asw[(rowa*16 + (slot ^ (rowa&7)))*8] = cvt8(*(const float4*)sp, *(const float4*)(sp+4));
        }
        STAGE_B(Wt, IN_DIM, kc)
        __syncthreads();
        MFMA_CORE(acc)
        __syncthreads();
    }
#pragma unroll
    for (int n = 0; n < 2; ++n){
        int col = wv*32 + n*16 + wl;
        float bb = b_[t*HID + col];
#pragma unroll
        for (int m = 0; m < 4; ++m){
#pragma unroll
            for (int i = 0; i < 4; ++i){
                int row = m*16 + kq*4 + i;
                if (base + row < cnt)
                    hp[(size_t)(gbase+row)*HID + col] = tanhf(acc[m][n][i] + bb);
            }
        }
    }
}

// ---------------- merged K/Q/V MFMA GEMM ----------------
// A (hp rows, permuted, linear) staged once; 3 weight passes.
// K/V written packed bf16: KVb[(node<<8) + (h*8+jj)*4 + {0,1:K(d0,d0+1) | 2,3:V}]

__global__ __launch_bounds__(256) void k_kqv(
    const float* __restrict__ hp,
    const short* __restrict__ Wtk, const float* __restrict__ bk_,
    const short* __restrict__ Wtq, const float* __restrict__ bq_,
    const short* __restrict__ Wtv, const float* __restrict__ bv_,
    const int* __restrict__ offT, const int* __restrict__ cntT,
    float* __restrict__ Qp, unsigned short* __restrict__ KVb)
{
    const int t = blockIdx.y;
    const int cnt = cntT[t];
    const int base = blockIdx.x * 64;
    if (base >= cnt) return;
    const int gbase = offT[t] + base;
    __shared__ short Asw[64*128];
    __shared__ short Bsw[128*128];
    const int tid = threadIdx.x;
    const int lane = tid & 63, wv = tid >> 6;
    const int wl = lane & 15, kq = lane >> 4, wl7 = wl & 7;

    for (int i_ = tid; i_ < 64*16; i_ += 256){
        int rowa = i_ >> 4, slot = i_ & 15;
        int grow = gbase + rowa; if (grow > N_NODES-1) grow = N_NODES-1;
        const float* sp = hp + (size_t)grow*HID + slot*8;
        *(bf16x8*)&Asw[(rowa*16 + (slot ^ (rowa&7)))*8] = cvt8(*(const float4*)sp, *(const float4*)(sp+4));
    }

    // ---- pass K ----
    {
        const short* Wt = Wtk + (size_t)t*HID*HID;
        STAGE_B(Wt, HID, 0)
        __syncthreads();
        f32x4 acc[4][2]; ZERO_ACC(acc)
        MFMA_CORE(acc)
        __syncthreads();
#pragma unroll
        for (int n = 0; n < 2; ++n){
            int col = wv*32 + n*16 + wl;
            float bb = bk_[t*HID + col];
            int slot = ((col>>4)*8 + ((col&15)>>1))*4 + (col&1);
#pragma unroll
            for (int m = 0; m < 4; ++m){
#pragma unroll
                for (int i = 0; i < 4; ++i){
                    int row = m*16 + kq*4 + i;
                    if (base + row < cnt)
                        KVb[((size_t)(gbase+row)<<8) + slot] = f2bf(acc[m][n][i] + bb);
                }
            }
        }
    }
    // ---- pass Q ----
    {
        const short* Wt = Wtq + (size_t)t*HID*HID;
        STAGE_B(Wt, HID, 0)
        __syncthreads();
        f32x4 acc[4][2]; ZERO_ACC(acc)
        MFMA_CORE(acc)
        __syncthreads();
#pragma unroll
        for (int n = 0; n < 2; ++n){
            int col = wv*32 + n*16 + wl;
            float bb = bq_[t*HID + col];
#pragma unroll
            for (int m = 0; m < 4; ++m){
#pragma unroll
                for (int i = 0; i < 4; ++i){
                    int row = m*16 + kq*4 + i;
                    if (base + row < cnt)
                        Qp[(size_t)(gbase+row)*HID + col] = acc[m][n][i] + bb;
                }
            }
        }
    }
    // ---- pass V ----
    {
        const short* Wt = Wtv + (size_t)t*HID*HID;
        STAGE_B(Wt, HID, 0)
        __syncthreads();
        f32x4 acc[4][2]; ZERO_ACC(acc)
        MFMA_CORE(acc)
        __syncthreads();
#pragma unroll
        for (int n = 0; n < 2; ++n){
            int col = wv*32 + n*16 + wl;
            float bb = bv_[t*HID + col];
            int slot = ((col>>4)*8 + ((col&15)>>1))*4 + (col&1) + 2;
#pragma unroll
            for (int m = 0; m < 4; ++m){
#pragma unroll
                for (int i = 0; i < 4; ++i){
                    int row = m*16 + kq*4 + i;
                    if (base + row < cnt)
                        KVb[((size_t)(gbase+row)<<8) + slot] = f2bf(acc[m][n][i] + bb);
                }
            }
        }
    }
}

// ---------------- per-node attention (bf16 KV, 1-wave workgroups) ----------------
// wave handles 2 nodes; lane = h*8+jj owns dims d0=2jj, d0+1 of head h.
// per-lane edge load: ushort4 {K[d0],K[d0+1],V[d0],V[d0+1]} bf16 (8B).

#define LOADKV4(S, P) \
    int pk##S##0 = epk[(P)+0], pk##S##1 = epk[(P)+1], pk##S##2 = epk[(P)+2], pk##S##3 = epk[(P)+3]; \
    ushort4 kv##S##0 = KVb4[((size_t)(pk##S##0 & 0xFFFF)<<6) + lane]; \
    ushort4 kv##S##1 = KVb4[((size_t)(pk##S##1 & 0xFFFF)<<6) + lane]; \
    ushort4 kv##S##2 = KVb4[((size_t)(pk##S##2 & 0xFFFF)<<6) + lane]; \
    ushort4 kv##S##3 = KVb4[((size_t)(pk##S##3 & 0xFFFF)<<6) + lane];

#define LOGIT_I(S, i) \
    float part##S##i; { \
        int r_ = pk##S##i >> 16; \
        float qa_ = (r_==0)?qa0##S:(r_==1)?qa1##S:(r_==2)?qa2##S:qa3##S; \
        float qb_ = (r_==0)?qb0##S:(r_==1)?qb1##S:(r_==2)?qb2##S:qb3##S; \
        part##S##i = fmaf(bf2f(kv##S##i.x), qa_, bf2f(kv##S##i.y) * qb_); \
    } \
    part##S##i += __shfl_xor(part##S##i, 1); \
    part##S##i += __shfl_xor(part##S##i, 2); \
    part##S##i += __shfl_xor(part##S##i, 4);

#define ACC_I(S, i) { \
    int r_ = pk##S##i >> 16; \
    float e_ = __expf(part##S##i - mn##S); \
    l##S += e_; \
    float vz_ = bf2f(kv##S##i.z), vw_ = bf2f(kv##S##i.w); \
    float w0_=(r_==0)?e_:0.f, w1_=(r_==1)?e_:0.f, w2_=(r_==2)?e_:0.f, w3_=(r_==3)?e_:0.f; \
    cx0##S = fmaf(w0_, vz_, cx0##S); cy0##S = fmaf(w0_, vw_, cy0##S); \
    cx1##S = fmaf(w1_, vz_, cx1##S); cy1##S = fmaf(w1_, vw_, cy1##S); \
    cx2##S = fmaf(w2_, vz_, cx2##S); cy2##S = fmaf(w2_, vw_, cy2##S); \
    cx3##S = fmaf(w3_, vz_, cx3##S); cy3##S = fmaf(w3_, vw_, cy3##S); }

#define BATCH4(S) \
    LOGIT_I(S,0) LOGIT_I(S,1) LOGIT_I(S,2) LOGIT_I(S,3) \
    float bm##S = fmaxf(fmaxf(part##S##0, part##S##1), fmaxf(part##S##2, part##S##3)); \
    float mn##S = fmaxf(m##S, bm##S); \
    float sc##S = __expf(m##S - mn##S); \
    m##S = mn##S; l##S *= sc##S; \
    cx0##S *= sc##S; cx1##S *= sc##S; cx2##S *= sc##S; cx3##S *= sc##S; \
    cy0##S *= sc##S; cy1##S *= sc##S; cy2##S *= sc##S; cy3##S *= sc##S; \
    ACC_I(S,0) ACC_I(S,1) ACC_I(S,2) ACC_I(S,3)

#define TAIL4(S, P, P1) { \
    int pk##S##0 = epk[P]; \
    int pk##S##1 = epk[((P)+1 < (P1)) ? (P)+1 : (P1)-1]; \
    int pk##S##2 = epk[((P)+2 < (P1)) ? (P)+2 : (P1)-1]; \
    int pk##S##3 = epk[((P)+3 < (P1)) ? (P)+3 : (P1)-1]; \
    ushort4 kv##S##0 = KVb4[((size_t)(pk##S##0 & 0xFFFF)<<6) + lane]; \
    ushort4 kv##S##1 = KVb4[((size_t)(pk##S##1 & 0xFFFF)<<6) + lane]; \
    ushort4 kv##S##2 = KVb4[((size_t)(pk##S##2 & 0xFFFF)<<6) + lane]; \
    ushort4 kv##S##3 = KVb4[((size_t)(pk##S##3 & 0xFFFF)<<6) + lane]; \
    LOGIT_I(S,0) LOGIT_I(S,1) LOGIT_I(S,2) LOGIT_I(S,3) \
    if ((P)+1 >= (P1)) part##S##1 = -INFINITY; \
    if ((P)+2 >= (P1)) part##S##2 = -INFINITY; \
    if ((P)+3 >= (P1)) part##S##3 = -INFINITY; \
    float bm##S = fmaxf(fmaxf(part##S##0, part##S##1), fmaxf(part##S##2, part##S##3)); \
    float mn##S = fmaxf(m##S, bm##S); \
    float sc##S = __expf(m##S - mn##S); \
    m##S = mn##S; l##S *= sc##S; \
    cx0##S *= sc##S; cx1##S *= sc##S; cx2##S *= sc##S; cx3##S *= sc##S; \
    cy0##S *= sc##S; cy1##S *= sc##S; cy2##S *= sc##S; cy3##S *= sc##S; \
    ACC_I(S,0) ACC_I(S,1) ACC_I(S,2) ACC_I(S,3) }

#define FINAL2(RIDX) { \
    const float* rm = rmT + (((size_t)((RIDX)*HH + h))*DKK + d0)*DKK; \
    float4 A0 = *(const float4*)(rm + 0),  A1 = *(const float4*)(rm + 4); \
    float4 A2 = *(const float4*)(rm + 8),  A3 = *(const float4*)(rm + 12); \
    float4 B0 = *(const float4*)(rm + 16), B1 = *(const float4*)(rm + 20); \
    float4 B2 = *(const float4*)(rm + 24), B3 = *(const float4*)(rm + 28); \
    float yA[16], yB[16]; \
    _Pragma("unroll") \
    for (int u = 0; u < 8; ++u){ \
        yA[2*u]   = __shfl(cx##RIDX##A, (h<<3) + u); \
        yA[2*u+1] = __shfl(cy##RIDX##A, (h<<3) + u); \
        yB[2*u]   = __shfl(cx##RIDX##B, (h<<3) + u); \
        yB[2*u+1] = __shfl(cy##RIDX##B, (h<<3) + u); \
    } \
    o0A += yA[0]*A0.x + yA[1]*A0.y + yA[2]*A0.z + yA[3]*A0.w \
         + yA[4]*A1.x + yA[5]*A1.y + yA[6]*A1.z + yA[7]*A1.w \
         + yA[8]*A2.x + yA[9]*A2.y + yA[10]*A2.z + yA[11]*A2.w \
         + yA[12]*A3.x + yA[13]*A3.y + yA[14]*A3.z + yA[15]*A3.w; \
    o1A += yA[0]*B0.x + yA[1]*B0.y + yA[2]*B0.z + yA[3]*B0.w \
         + yA[4]*B1.x + yA[5]*B1.y + yA[6]*B1.z + yA[7]*B1.w \
         + yA[8]*B2.x + yA[9]*B2.y + yA[10]*B2.z + yA[11]*B2.w \
         + yA[12]*B3.x + yA[13]*B3.y + yA[14]*B3.z + yA[15]*B3.w; \
    o0B += yB[0]*A0.x + yB[1]*A0.y + yB[2]*A0.z + yB[3]*A0.w \
         + yB[4]*A1.x + yB[5]*A1.y + yB[6]*A1.z + yB[7]*A1.w \
         + yB[8]*A2.x + yB[9]*A2.y + yB[10]*A2.z + yB[11]*A2.w \
         + yB[12]*A3.x + yB[13]*A3.y + yB[14]*A3.z + yB[15]*A3.w; \
    o1B += yB[0]*B0.x + yB[1]*B0.y + yB[2]*B0.z + yB[3]*B0.w \
         + yB[4]*B1.x + yB[5]*B1.y + yB[6]*B1.z + yB[7]*B1.w \
         + yB[8]*B2.x + yB[9]*B2.y + yB[10]*B2.z + yB[11]*B2.w \
         + yB[12]*B3.x + yB[13]*B3.y + yB[14]*B3.z + yB[15]*B3.w; }

__global__ __launch_bounds__(64) void k_attn(
    const float* __restrict__ Qp, const ushort4* __restrict__ KVb4,
    const float* __restrict__ Ratt, const float* __restrict__ rmT,
    const float* __restrict__ pri,
    const int* __restrict__ off, const int* __restrict__ epk,
    float* __restrict__ agg)
{
    const int n0 = blockIdx.x*2;
    if (n0 >= N_NODES) return;
    const bool hasB = (n0 + 1) < N_NODES;
    const int lane = threadIdx.x & 63;
    const int h  = lane >> 3;
    const int d0 = (lane & 7) * 2;

    const float* qpA = Qp + (size_t)n0*HID + h*DKK;
    const float* qpB = Qp + (size_t)(hasB ? n0+1 : n0)*HID + h*DKK;
    float qvA[16], qvB[16];
#pragma unroll
    for (int u = 0; u < 4; ++u){
        float4 ta = *(const float4*)(qpA + 4*u);
        float4 tb = *(const float4*)(qpB + 4*u);
        qvA[4*u+0]=ta.x; qvA[4*u+1]=ta.y; qvA[4*u+2]=ta.z; qvA[4*u+3]=ta.w;
        qvB[4*u+0]=tb.x; qvB[4*u+1]=tb.y; qvB[4*u+2]=tb.z; qvB[4*u+3]=tb.w;
    }

    float qa0A,qa1A,qa2A,qa3A,qb0A,qb1A,qb2A,qb3A;
    float qa0B,qa1B,qa2B,qa3B,qb0B,qb1B,qb2B,qb3B;
#pragma unroll
    for (int r = 0; r < RR; ++r){
        const float* ar = Ratt + (((size_t)(r*HH + h))*DKK + d0)*DKK;
        float s0A=0.f, s1A=0.f, s0B=0.f, s1B=0.f;
#pragma unroll
        for (int u = 0; u < 4; ++u){
            float4 a0 = *(const float4*)(ar + 4*u);
            float4 a1 = *(const float4*)(ar + DKK + 4*u);
            s0A += a0.x*qvA[4*u+0] + a0.y*qvA[4*u+1] + a0.z*qvA[4*u+2] + a0.w*qvA[4*u+3];
            s1A += a1.x*qvA[4*u+0] + a1.y*qvA[4*u+1] + a1.z*qvA[4*u+2] + a1.w*qvA[4*u+3];
            s0B += a0.x*qvB[4*u+0] + a0.y*qvB[4*u+1] + a0.z*qvB[4*u+2] + a0.w*qvB[4*u+3];
            s1B += a1.x*qvB[4*u+0] + a1.y*qvB[4*u+1] + a1.z*qvB[4*u+2] + a1.w*qvB[4*u+3];
        }
        float pr = pri[r*HH + h] * 0.25f;
        s0A *= pr; s1A *= pr; s0B *= pr; s1B *= pr;
        if      (r == 0){ qa0A=s0A; qb0A=s1A; qa0B=s0B; qb0B=s1B; }
        else if (r == 1){ qa1A=s0A; qb1A=s1A; qa1B=s0B; qb1B=s1B; }
        else if (r == 2){ qa2A=s0A; qb2A=s1A; qa2B=s0B; qb2B=s1B; }
        else            { qa3A=s0A; qb3A=s1A; qa3B=s0B; qb3B=s1B; }
    }

    float mA=-INFINITY, lA=0.f, cx0A=0.f,cx1A=0.f,cx2A=0.f,cx3A=0.f, cy0A=0.f,cy1A=0.f,cy2A=0.f,cy3A=0.f;
    float mB=-INFINITY, lB=0.f, cx0B=0.f,cx1B=0.f,cx2B=0.f,cx3B=0.f, cy0B=0.f,cy1B=0.f,cy2B=0.f,cy3B=0.f;

    int pa = off[n0],  ea = off[n0+1];
    int pb = 0, eb = 0;
    if (hasB){ pb = ea; eb = off[n0+2]; }

    while (pa + 4 <= ea && pb + 4 <= eb){
        LOADKV4(A, pa)
        LOADKV4(B, pb)
        BATCH4(A)
        BATCH4(B)
        pa += 4; pb += 4;
    }
    while (pa + 4 <= ea){
        LOADKV4(A, pa)
        BATCH4(A)
        pa += 4;
    }
    while (pb + 4 <= eb){
        LOADKV4(B, pb)
        BATCH4(B)
        pb += 4;
    }
    if (pa < ea) TAIL4(A, pa, ea)
    if (pb < eb) TAIL4(B, pb, eb)

    float o0A=0.f, o1A=0.f, o0B=0.f, o1B=0.f;
    FINAL2(0)
    FINAL2(1)
    FINAL2(2)
    FINAL2(3)

    const float invA = 1.f / fmaxf(lA, 1e-9f);
    *(float2*)(agg + (size_t)n0*HID + h*DKK + d0) = make_float2(o0A*invA, o1A*invA);
    if (hasB){
        const float invB = 1.f / fmaxf(lB, 1e-9f);
        *(float2*)(agg + (size_t)(n0+1)*HID + h*DKK + d0) = make_float2(o0B*invB, o1B*invB);
    }
}

// ---------------- output MFMA GEMM: gelu(aggp) @ Wa + blend (+LN+ReLU) ----------------

template<bool USE_LN>
__global__ __launch_bounds__(256) void k_out(
    const float* __restrict__ aggp, const short* __restrict__ Wta, const float* __restrict__ ba_,
    const float* __restrict__ hin, const float* __restrict__ skipl,
    const float* __restrict__ gam, const float* __restrict__ bet,
    const int* __restrict__ nperm, const int* __restrict__ offT, const int* __restrict__ cntT,
    float* __restrict__ hout)
{
    const int t = blockIdx.y;
    const int cnt = cntT[t];
    const int base = blockIdx.x * 64;
    if (base >= cnt) return;
    const int gbase = offT[t] + base;
    __shared__ short Asw[64*128];
    __shared__ short Bsw[128*128];
    __shared__ int nid[64];
    const int tid = threadIdx.x;
    if (!USE_LN && tid < 64){
        int ii = base + tid;
        nid[tid] = (ii < cnt) ? nperm[offT[t] + ii] : -1;
    }
    const int lane = tid & 63, wv = tid >> 6;
    const int wl = lane & 15, kq = lane >> 4, wl7 = wl & 7;

    for (int i_ = tid; i_ < 64*16; i_ += 256){
        int rowa = i_ >> 4, slot = i_ & 15;
        int grow = gbase + rowa; if (grow > N_NODES-1) grow = N_NODES-1;
        const float* sp = aggp + (size_t)grow*HID + slot*8;
        float4 f0 = *(const float4*)sp, f1 = *(const float4*)(sp+4);
        f0.x=geluf(f0.x); f0.y=geluf(f0.y); f0.z=geluf(f0.z); f0.w=geluf(f0.w);
        f1.x=geluf(f1.x); f1.y=geluf(f1.y); f1.z=geluf(f1.z); f1.w=geluf(f1.w);
        *(bf16x8*)&Asw[(rowa*16 + (slot ^ (rowa&7)))*8] = cvt8(f0, f1);
    }
    {
        const short* Wt = Wta + (size_t)t*HID*HID;
        STAGE_B(Wt, HID, 0)
    }
    __syncthreads();
    f32x4 acc[4][2]; ZERO_ACC(acc)
    MFMA_CORE(acc)
    __syncthreads();

    float* smemf = (float*)Bsw;
#pragma unroll
    for (int n = 0; n < 2; ++n){
        int col = wv*32 + n*16 + wl;
#pragma unroll
        for (int m = 0; m < 4; ++m){
#pragma unroll
            for (int i = 0; i < 4; ++i){
                int row = m*16 + kq*4 + i;
                smemf[row*128 + col] = acc[m][n][i];
            }
        }
    }
    __syncthreads();

    const float alpha = 1.f / (1.f + __expf(-skipl[t]));
    const float onem = 1.f - alpha;
    const int row = tid >> 2;
    const int part = tid & 3;
    const int cbase = part * 32;
    float vals[32];
    float s = 0.f, s2 = 0.f;
    int growr = gbase + row; if (growr > N_NODES-1) growr = N_NODES-1;
#pragma unroll
    for (int u = 0; u < 8; ++u){
        float4 d  = *(float4*)&smemf[row*128 + cbase + u*4];
        float4 bb = *(const float4*)&ba_[t*HID + cbase + u*4];
        float4 hv = *(const float4*)&hin[(size_t)growr*HID + cbase + u*4];
        float v0 = (d.x + bb.x)*alpha + hv.x*onem;
        float v1 = (d.y + bb.y)*alpha + hv.y*onem;
        float v2 = (d.z + bb.z)*alpha + hv.z*onem;
        float v3 = (d.w + bb.w)*alpha + hv.w*onem;
        vals[u*4+0]=v0; vals[u*4+1]=v1; vals[u*4+2]=v2; vals[u*4+3]=v3;
        s += v0+v1+v2+v3;
        s2 += v0*v0+v1*v1+v2*v2+v3*v3;
    }
    if (USE_LN){
        s  += __shfl_xor(s, 1);  s  += __shfl_xor(s, 2);
        s2 += __shfl_xor(s2, 1); s2 += __shfl_xor(s2, 2);
        float mu = s * (1.f/128.f);
        float var = s2 * (1.f/128.f) - mu*mu;
        float rstd = rsqrtf(var + 1e-5f);
        if (base + row < cnt){
#pragma unroll
            for (int u = 0; u < 8; ++u){
                float4 g4 = *(const float4*)&gam[t*HID + cbase + u*4];
                float4 e4 = *(const float4*)&bet[t*HID + cbase + u*4];
                float4 r4;
                r4.x = fmaxf((vals[u*4+0]-mu)*rstd*g4.x + e4.x, 0.f);
                r4.y = fmaxf((vals[u*4+1]-mu)*rstd*g4.y + e4.y, 0.f);
                r4.z = fmaxf((vals[u*4+2]-mu)*rstd*g4.z + e4.z, 0.f);
                r4.w = fmaxf((vals[u*4+3]-mu)*rstd*g4.w + e4.w, 0.f);
                *(float4*)&hout[(size_t)(gbase+row)*HID + cbase + u*4] = r4;
            }
        }
    } else {
        __syncthreads();
        int node = (base + row < cnt) ? nid[row] : -1;
        if (node >= 0){
#pragma unroll
            for (int u = 0; u < 8; ++u){
                float4 r4 = make_float4(vals[u*4+0], vals[u*4+1], vals[u*4+2], vals[u*4+3]);
                *(float4*)&hout[(size_t)node*HID + cbase + u*4] = r4;
            }
        }
    }
}

// ---------------- launch ----------------

extern "C" void kernel_launch(void* const* d_in, const int* in_sizes, int n_in,
                              void* d_out, int out_size, void* d_ws, size_t ws_size,
                              hipStream_t stream)
{
    const float* x         = (const float*)d_in[0];
    const int*   node_types= (const int*)  d_in[1];
    const int*   edge_index= (const int*)  d_in[2];
    const int*   edge_types= (const int*)  d_in[3];
    const float* W_adapt   = (const float*)d_in[4];
    const float* b_adapt   = (const float*)d_in[5];
    const float* Wk        = (const float*)d_in[6];
    const float* bk        = (const float*)d_in[7];
    const float* Wq        = (const float*)d_in[8];
    const float* bq        = (const float*)d_in[9];
    const float* Wv        = (const float*)d_in[10];
    const float* bv        = (const float*)d_in[11];
    const float* Wa        = (const float*)d_in[12];
    const float* ba        = (const float*)d_in[13];
    const float* rel_pri   = (const float*)d_in[14];
    const float* rel_att   = (const float*)d_in[15];
    const float* rel_msg   = (const float*)d_in[16];
    const float* skip      = (const float*)d_in[17];
    const float* ln_g      = (const float*)d_in[18];
    const float* ln_b      = (const float*)d_in[19];
    float* out = (float*)d_out;

    char* p = (char*)d_ws;
    auto alloc = [&](size_t bytes) -> void* {
        void* q = (void*)p;
        p += (bytes + 255) & ~(size_t)255;
        return q;
    };
    float* xp    = (float*)alloc((size_t)N_NODES*IN_DIM*4);
    float* hp    = (float*)alloc((size_t)N_NODES*HID*4);
    float* Qp    = (float*)alloc((size_t)N_NODES*HID*4);
    unsigned short* KVb = (unsigned short*)alloc((size_t)N_NODES*256*2);
    float* aggp  = (float*)alloc((size_t)N_NODES*HID*4);
    float* rmT   = (float*)alloc((size_t)2*RR*HH*DKK*DKK*4);
    short* Wta   = (short*)alloc((size_t)TT*IN_DIM*HID*2);
    short* Wtk   = (short*)alloc((size_t)2*TT*HID*HID*2);
    short* Wtq   = (short*)alloc((size_t)2*TT*HID*HID*2);
    short* Wtv   = (short*)alloc((size_t)2*TT*HID*HID*2);
    short* Wtao  = (short*)alloc((size_t)2*TT*HID*HID*2);
    int* ib      = (int*)alloc((size_t)(2*N_NODES + 8)*4);
    int* deg  = ib;
    int* tmpN = ib + N_NODES;
    int* cntT = ib + 2*N_NODES;
    int* tmpT = ib + 2*N_NODES + 4;
    int* off   = (int*)alloc((size_t)(N_NODES+1)*4);
    int* offT  = (int*)alloc(16);
    int* epk   = (int*)alloc((size_t)E_EDGES*4);
    int* nperm = (int*)alloc((size_t)N_NODES*4);
    int* inv   = (int*)alloc((size_t)N_NODES*4);

    const int* esrc = edge_index;
    const int* edst = edge_index + E_EDGES;

    hipMemsetAsync(ib, 0, (size_t)(2*N_NODES + 8)*4, stream);
    k_hist_nodes<<<(N_NODES+255)/256, 256, 0, stream>>>(node_types, cntT, N_NODES);
    k_offT<<<1, 1, 0, stream>>>(cntT, offT);
    k_scatter_nodes<<<(N_NODES+255)/256, 256, 0, stream>>>(node_types, offT, tmpT, nperm, inv, N_NODES);
    k_permute_x<<<(N_NODES+3)/4, 256, 0, stream>>>(x, nperm, xp);
    k_hist_edges<<<(E_EDGES+255)/256, 256, 0, stream>>>(edst, inv, deg, E_EDGES);
    k_scan<<<1, 1024, 0, stream>>>(deg, off, N_NODES);
    k_scatter_edges<<<(E_EDGES+255)/256, 256, 0, stream>>>(esrc, edst, edge_types, inv, off, tmpN, epk, E_EDGES);
    k_transpose_rmsg<<<(2*RR*HH*DKK*DKK+255)/256, 256, 0, stream>>>(rel_msg, rmT);
    k_cvt_w<<<(TT*IN_DIM*HID+255)/256, 256, 0, stream>>>(W_adapt, Wta, IN_DIM, HID, TT*IN_DIM*HID);
    k_cvt_w<<<(2*TT*HID*HID+255)/256, 256, 0, stream>>>(Wk, Wtk, HID, HID, 2*TT*HID*HID);
    k_cvt_w<<<(2*TT*HID*HID+255)/256, 256, 0, stream>>>(Wq, Wtq, HID, HID, 2*TT*HID*HID);
    k_cvt_w<<<(2*TT*HID*HID+255)/256, 256, 0, stream>>>(Wv, Wtv, HID, HID, 2*TT*HID*HID);
    k_cvt_w<<<(2*TT*HID*HID+255)/256, 256, 0, stream>>>(Wa, Wtao, HID, HID, 2*TT*HID*HID);

    dim3 gg((N_NODES+63)/64, TT);
    k_adapt<<<gg, 256, 0, stream>>>(xp, Wta, b_adapt, offT, cntT, hp);

    for (int l = 0; l < 2; ++l){
        const size_t WOFF = (size_t)l*TT*HID*HID;
        const size_t BOFF = (size_t)l*TT*HID;
        k_kqv<<<gg, 256, 0, stream>>>(hp, Wtk+WOFF, bk+BOFF, Wtq+WOFF, bq+BOFF, Wtv+WOFF, bv+BOFF,
                                      offT, cntT, Qp, KVb);
        k_attn<<<(N_NODES+1)/2, 64, 0, stream>>>(Qp, (const ushort4*)KVb,
            rel_att + (size_t)l*RR*HH*DKK*DKK,
            rmT + (size_t)l*RR*HH*DKK*DKK,
            rel_pri + (size_t)l*RR*HH,
            off, epk, aggp);
        if (l == 0)
            k_out<true><<<gg, 256, 0, stream>>>(aggp, Wtao+WOFF, ba+BOFF, hp, skip + l*TT,
                                                ln_g, ln_b, nperm, offT, cntT, hp);
        else
            k_out<false><<<gg, 256, 0, stream>>>(aggp, Wtao+WOFF, ba+BOFF, hp, skip + l*TT,
                                                 ln_g, ln_b, nperm, offT, cntT, out);
    }
}